// Round 8
// baseline (1225.976 us; speedup 1.0000x reference)
//
#include <hip/hip_runtime.h>
#include <cmath>

#define BB 8
#define DD 1024
#define NP 4096
#define KC 32
#define HH 512
#define PP 128
#define NJB 16          // sinkhorn blocks per batch
#define BN_EPS 1e-5f

typedef unsigned short u16;
typedef unsigned long long u64;
typedef short s16x8 __attribute__((ext_vector_type(8)));
typedef float f32x4 __attribute__((ext_vector_type(4)));

// ---------------- wave helpers ----------------
__device__ __forceinline__ float waveReduceSum(float v) {
#pragma unroll
  for (int o = 32; o > 0; o >>= 1) v += __shfl_down(v, o, 64);
  return v;
}

// ---------------- bf16 3-way split: y = h + m + l + O(2^-24 |y|) ----------
__device__ __forceinline__ void split3(float y, short& h, short& m, short& l) {
  unsigned uy = __float_as_uint(y);
  h = (short)(uy >> 16);
  float r1 = y - __uint_as_float(uy & 0xFFFF0000u);
  unsigned um = __float_as_uint(r1);
  m = (short)(um >> 16);
  float r2 = r1 - __uint_as_float(um & 0xFFFF0000u);
  l = (short)(__float_as_uint(r2) >> 16);
}

// ---------------- W pre-permute + 3-split (+ zero BN accumulators with idle blocks)
__global__ __launch_bounds__(256) void convW3_all(
    const float* __restrict__ W1, u16* __restrict__ h1, u16* __restrict__ m1, u16* __restrict__ l1,
    const float* __restrict__ W2, u16* __restrict__ h2, u16* __restrict__ m2, u16* __restrict__ l2,
    const float* __restrict__ W3, u16* __restrict__ h3, u16* __restrict__ m3, u16* __restrict__ l3,
    float* __restrict__ zbuf) {
  int z = blockIdx.z;
  // z==2 only uses mt==0; idle blocks (mt>=1) zero the 24KB BN-accumulator region
  if (z == 2 && blockIdx.x >= 1) {
    int id = (blockIdx.x - 1) * 32 + blockIdx.y;   // 0..95
    if (id < 24) zbuf[id * 256 + threadIdx.x] = 0.f;
    return;
  }
  const float* W; u16 *hb, *mb, *lb; int K, BM, MTt, KCH;
  if (z == 0)      { W = W1; hb = h1; mb = m1; lb = l1; K = 1024; BM = 128; MTt = 4; KCH = 32; }
  else if (z == 1) { W = W2; hb = h2; mb = m2; lb = l2; K = 512;  BM = 128; MTt = 4; KCH = 16; }
  else             { W = W3; hb = h3; mb = m3; lb = l3; K = 512;  BM = 32;  MTt = 1; KCH = 16; }
  int mt = blockIdx.x, kc = blockIdx.y;
  if (mt >= MTt || kc >= KCH) return;
  const int AU = BM * 4;
  for (int u = threadIdx.x; u < AU; u += 256) {
    int q = u / BM, m = u % BM;
    const float* wp = W + (size_t)(mt * BM + m) * K + kc * 32 + q * 8;
    s16x8 hv, mv, lv;
#pragma unroll
    for (int j = 0; j < 8; j++) {
      short h, mm, l; split3(wp[j], h, mm, l);
      hv[j] = h; mv[j] = mm; lv[j] = l;
    }
    size_t ob = ((size_t)(mt * KCH + kc)) * (size_t)(BM * 32) + (size_t)u * 8;
    *(s16x8*)(hb + ob) = hv;
    *(s16x8*)(mb + ob) = mv;
    *(s16x8*)(lb + ob) = lv;
  }
}

// ---------------- bf16x3 MFMA GEMM, reg-prefetch pipelined.
// BNRELU: consumer-side BN (scale/shift computed in-block from raw sums).
// ACCST:  producer-side per-channel sum/sumsq accumulation (replaces bnstats).
// SMAX:   fused softmax-over-M epilogue (replaces softmax_pi; requires WM==1, BM==KC).
template<int BM, int MBLK, int MT, int NT, int WM, bool BNRELU, bool ACCST, bool SMAX>
__global__ __launch_bounds__(256) void gemm_mfma3(
    const u16* __restrict__ wh, const u16* __restrict__ wmid, const u16* __restrict__ wl,
    const float* __restrict__ bias, const float* __restrict__ X,
    const float* __restrict__ insum, const float* __restrict__ insq,
    const float* __restrict__ bng, const float* __restrict__ bnb, float cnt,
    float* __restrict__ Y, int K, int M,
    float* __restrict__ gsum, float* __restrict__ gsq,
    float* __restrict__ score, float* __restrict__ lse, float* __restrict__ piraw) {
  __shared__ s16x8 AhS[BM * 4], AmS[BM * 4], AlS[BM * 4];
  __shared__ s16x8 BhS[512], BmS[512], BlS[512];
  __shared__ float scS[512], shS[512];
  const int KCH = K / 32;
  const int tid = threadIdx.x;
  const int bz = blockIdx.z;
  int bid = blockIdx.x;
  int xs = bid & 7, rr = bid >> 3;
  int m_idx = rr % MBLK;
  int n_idx = xs + 8 * (rr / MBLK);

  const int w = tid >> 6, l = tid & 63, q = l >> 4, col = l & 15;
  const int wm = (WM == 1) ? 0 : (w >> 1);
  const int wn = (WM == 1) ? w : (w & 1);
  constexpr int NA = (BM * 4 + 255) / 256;

  if (BNRELU) {
    for (int c0 = tid; c0 < K; c0 += 256) {
      float mean = insum[c0] / cnt;
      float var = insq[c0] / cnt - mean * mean;
      float sc = bng[c0] / sqrtf(var + BN_EPS);
      scS[c0] = sc; shS[c0] = bnb[c0] - mean * sc;
    }
    __syncthreads();
  }

  f32x4 acc[MT][NT];
#pragma unroll
  for (int i = 0; i < MT; i++)
#pragma unroll
    for (int j = 0; j < NT; j++) { acc[i][j][0] = 0.f; acc[i][j][1] = 0.f; acc[i][j][2] = 0.f; acc[i][j][3] = 0.f; }

  const short* Ah = (const short*)AhS;
  const short* Am = (const short*)AmS;
  const short* Al = (const short*)AlS;
  const short* Bh = (const short*)BhS;
  const short* Bm = (const short*)BmS;
  const short* Bl = (const short*)BlS;

  const float* Xb = X + (size_t)bz * (size_t)K * NP + (size_t)n_idx * 128;
  const size_t abase = (size_t)m_idx * KCH * (size_t)(BM * 32);

  s16x8 rAh[NA], rAm[NA], rAl[NA];
  float rB[2][8];

  {
    const s16x8* awh = (const s16x8*)(wh + abase);
    const s16x8* awm = (const s16x8*)(wmid + abase);
    const s16x8* awl = (const s16x8*)(wl + abase);
#pragma unroll
    for (int t = 0; t < NA; t++) {
      int u = tid + t * 256;
      if (u < BM * 4) { rAh[t] = awh[u]; rAm[t] = awm[u]; rAl[t] = awl[u]; }
    }
#pragma unroll
    for (int t = 0; t < 2; t++) {
      int u = tid + t * 256;
      int qq = u >> 7, n = u & 127;
      const float* fp = Xb + (size_t)(qq * 8) * NP + n;
#pragma unroll
      for (int j = 0; j < 8; j++) {
        float y = fp[(size_t)j * NP];
        if (BNRELU) y = fmaxf(fmaf(y, scS[qq * 8 + j], shS[qq * 8 + j]), 0.f);
        rB[t][j] = y;
      }
    }
  }

  for (int kc = 0; kc < KCH; kc++) {
#pragma unroll
    for (int t = 0; t < NA; t++) {
      int u = tid + t * 256;
      if (u < BM * 4) { AhS[u] = rAh[t]; AmS[u] = rAm[t]; AlS[u] = rAl[t]; }
    }
#pragma unroll
    for (int t = 0; t < 2; t++) {
      int u = tid + t * 256;
      s16x8 hv, mv, lv;
#pragma unroll
      for (int j = 0; j < 8; j++) {
        short h, mm, ll; split3(rB[t][j], h, mm, ll);
        hv[j] = h; mv[j] = mm; lv[j] = ll;
      }
      BhS[u] = hv; BmS[u] = mv; BlS[u] = lv;
    }
    __syncthreads();

    if (kc + 1 < KCH) {
      size_t ab = abase + (size_t)(kc + 1) * (size_t)(BM * 32);
      const s16x8* awh = (const s16x8*)(wh + ab);
      const s16x8* awm = (const s16x8*)(wmid + ab);
      const s16x8* awl = (const s16x8*)(wl + ab);
#pragma unroll
      for (int t = 0; t < NA; t++) {
        int u = tid + t * 256;
        if (u < BM * 4) { rAh[t] = awh[u]; rAm[t] = awm[u]; rAl[t] = awl[u]; }
      }
      const int kp = (kc + 1) * 32;
#pragma unroll
      for (int t = 0; t < 2; t++) {
        int u = tid + t * 256;
        int qq = u >> 7, n = u & 127;
        const float* fp = Xb + (size_t)(kp + qq * 8) * NP + n;
#pragma unroll
        for (int j = 0; j < 8; j++) {
          float y = fp[(size_t)j * NP];
          if (BNRELU) y = fmaxf(fmaf(y, scS[kp + qq * 8 + j], shS[kp + qq * 8 + j]), 0.f);
          rB[t][j] = y;
        }
      }
    }

    s16x8 ah[MT], am[MT], al[MT];
#pragma unroll
    for (int i = 0; i < MT; i++) {
      int off = (q * BM + wm * (MT * 16) + i * 16 + col) * 8;
      ah[i] = *(const s16x8*)(Ah + off);
      am[i] = *(const s16x8*)(Am + off);
      al[i] = *(const s16x8*)(Al + off);
    }
    __builtin_amdgcn_s_setprio(1);
#pragma unroll
    for (int j = 0; j < NT; j++) {
      int offb = (q * 128 + wn * (NT * 16) + j * 16 + col) * 8;
      s16x8 bh = *(const s16x8*)(Bh + offb);
      s16x8 bm = *(const s16x8*)(Bm + offb);
      s16x8 bl = *(const s16x8*)(Bl + offb);
#pragma unroll
      for (int i = 0; i < MT; i++) {
        acc[i][j] = __builtin_amdgcn_mfma_f32_16x16x32_bf16(ah[i], bh, acc[i][j], 0, 0, 0);
        acc[i][j] = __builtin_amdgcn_mfma_f32_16x16x32_bf16(ah[i], bm, acc[i][j], 0, 0, 0);
        acc[i][j] = __builtin_amdgcn_mfma_f32_16x16x32_bf16(am[i], bh, acc[i][j], 0, 0, 0);
        acc[i][j] = __builtin_amdgcn_mfma_f32_16x16x32_bf16(ah[i], bl, acc[i][j], 0, 0, 0);
        acc[i][j] = __builtin_amdgcn_mfma_f32_16x16x32_bf16(am[i], bm, acc[i][j], 0, 0, 0);
        acc[i][j] = __builtin_amdgcn_mfma_f32_16x16x32_bf16(al[i], bh, acc[i][j], 0, 0, 0);
      }
    }
    __builtin_amdgcn_s_setprio(0);
    __syncthreads();
  }

  if (!SMAX) {
    // ---- store + optional per-channel sum/sumsq accumulation (bnstats fused)
    float* red = (float*)AhS;   // main loop done (last iter ended in syncthreads)
    if (ACCST) {
      if (tid < 2 * BM) red[tid] = 0.f;
      __syncthreads();
    }
#pragma unroll
    for (int i = 0; i < MT; i++) {
#pragma unroll
      for (int r = 0; r < 4; r++) {
        int ml = wm * (MT * 16) + i * 16 + q * 4 + r;
        int m = m_idx * BM + ml;
        float bv = bias[m];
        float ys = 0.f, yq = 0.f;
#pragma unroll
        for (int j = 0; j < NT; j++) {
          int n = n_idx * 128 + wn * (NT * 16) + j * 16 + col;
          float y = acc[i][j][r] + bv;
          Y[((size_t)bz * M + m) * 4096 + n] = y;
          ys += y; yq = fmaf(y, y, yq);
        }
        if (ACCST) {
          atomicAdd(&red[ml * 2], ys);
          atomicAdd(&red[ml * 2 + 1], yq);
        }
      }
    }
    if (ACCST) {
      __syncthreads();
      if (tid < BM) {
        atomicAdd(&gsum[m_idx * BM + tid], red[tid * 2]);
        atomicAdd(&gsq[m_idx * BM + tid], red[tid * 2 + 1]);
      }
    }
  } else {
    // ---- fused softmax over M (=KC) per column (softmax_pi replacement).
    // WM==1, BM==32: block holds ALL m for its 128 columns; a column's 32
    // m-values live in the 4 same-wave lanes q=0..3 -> shfl_xor(16/32) reduce.
    float yv[MT][NT][4];
#pragma unroll
    for (int i = 0; i < MT; i++) {
#pragma unroll
      for (int r = 0; r < 4; r++) {
        int m = i * 16 + q * 4 + r;
        float bv = bias[m];
#pragma unroll
        for (int j = 0; j < NT; j++) {
          int n = n_idx * 128 + wn * (NT * 16) + j * 16 + col;
          float y = acc[i][j][r] + bv;
          Y[((size_t)bz * M + m) * 4096 + n] = y;
          yv[i][j][r] = y;
        }
      }
    }
    float* redP = (float*)AhS;
    if (tid < KC) redP[tid] = 0.f;
    __syncthreads();
    float pl[MT][4];
#pragma unroll
    for (int i = 0; i < MT; i++)
#pragma unroll
      for (int r = 0; r < 4; r++) pl[i][r] = 0.f;
#pragma unroll
    for (int j = 0; j < NT; j++) {
      float mx = -1e30f;
#pragma unroll
      for (int i = 0; i < MT; i++)
#pragma unroll
        for (int r = 0; r < 4; r++) mx = fmaxf(mx, yv[i][j][r]);
      mx = fmaxf(mx, __shfl_xor(mx, 16, 64));
      mx = fmaxf(mx, __shfl_xor(mx, 32, 64));
      float e[MT][4]; float s = 0.f;
#pragma unroll
      for (int i = 0; i < MT; i++)
#pragma unroll
        for (int r = 0; r < 4; r++) { e[i][r] = expf(yv[i][j][r] - mx); s += e[i][r]; }
      s += __shfl_xor(s, 16, 64);
      s += __shfl_xor(s, 32, 64);
      float inv = 1.f / s;
      int n = n_idx * 128 + wn * (NT * 16) + j * 16 + col;
#pragma unroll
      for (int i = 0; i < MT; i++)
#pragma unroll
        for (int r = 0; r < 4; r++) {
          float sv = e[i][r] * inv;
          int m = i * 16 + q * 4 + r;
          score[((size_t)bz * KC + m) * NP + n] = sv;
          pl[i][r] += sv;
        }
      if ((tid & 48) == 0) lse[(size_t)bz * NP + n] = mx + logf(s);
    }
#pragma unroll
    for (int i = 0; i < MT; i++)
#pragma unroll
      for (int r = 0; r < 4; r++) atomicAdd(&redP[i * 16 + q * 4 + r], pl[i][r]);
    __syncthreads();
    if (tid < KC) atomicAdd(&piraw[bz * KC + tid], redP[tid]);
  }
}

// ---------------- vlad accumulation (split over n, atomic) — RAW (undivided) vlad
__global__ __launch_bounds__(256) void vlad_accum(
    const float* __restrict__ feat, const float* __restrict__ score, float* __restrict__ vlad) {
  const int SPLIT_LEN = NP / 8;
  int sp = blockIdx.x, dt = blockIdx.y, b = blockIdx.z;
  int d0 = dt * 128;
  int n_start = sp * SPLIT_LEN;
  __shared__ float As[32][132];
  __shared__ float Bs[32][36];
  int tid = threadIdx.x;
  int tx = tid % 16;
  int ty = tid / 16;
  float acc[8][2] = {};
  const float* fb = feat + (size_t)b * DD * NP;
  const float* sb = score + (size_t)b * KC * NP;
  for (int nc = 0; nc < SPLIT_LEN; nc += 32) {
    int n0 = n_start + nc;
    for (int i = tid; i < 128 * 32; i += 256) {
      int r = i >> 5, c = i & 31;
      As[c][r] = fb[(size_t)(d0 + r) * NP + n0 + c];
    }
    for (int i = tid; i < 32 * 32; i += 256) {
      int r = i >> 5, c = i & 31;
      Bs[c][r] = sb[(size_t)r * NP + n0 + c];
    }
    __syncthreads();
#pragma unroll 4
    for (int kk = 0; kk < 32; kk++) {
      float ra[8], rb[2];
#pragma unroll
      for (int i = 0; i < 8; i++) ra[i] = As[kk][ty * 8 + i];
      rb[0] = Bs[kk][tx * 2]; rb[1] = Bs[kk][tx * 2 + 1];
#pragma unroll
      for (int i = 0; i < 8; i++) { acc[i][0] = fmaf(ra[i], rb[0], acc[i][0]); acc[i][1] = fmaf(ra[i], rb[1], acc[i][1]); }
    }
    __syncthreads();
  }
#pragma unroll
  for (int i = 0; i < 8; i++)
#pragma unroll
    for (int j = 0; j < 2; j++)
      atomicAdd(&vlad[((size_t)b * DD + d0 + ty * 8 + i) * KC + tx * 2 + j], acc[i][j]);
}

// ---------------- cost dot accumulation + fused: pi-divide (vlad_fin), ||f_n||^2,
// ||mu_k||^2 partials, and gmax (per-d max over k) from nt==0 blocks.
__global__ __launch_bounds__(256) void cost_accum(
    const float* __restrict__ feat, const float* __restrict__ vlad,
    const float* __restrict__ piraw, float* __restrict__ costd,
    float* __restrict__ nfsq, float* __restrict__ nmusq, float* __restrict__ gmax) {
  int sp = blockIdx.x, nt = blockIdx.y, b = blockIdx.z;
  int n0 = nt * 128;
  int d_start = sp * (DD / 4);
  __shared__ float As[32][132];
  __shared__ float Bs[32][36];
  __shared__ float nfs[128];
  __shared__ float piS[KC];
  __shared__ float nms[KC];
  int tid = threadIdx.x;
  int tx = tid % 16;
  int ty = tid / 16;
  if (tid < KC) { piS[tid] = fmaxf(piraw[b * KC + tid], 1e-4f); nms[tid] = 0.f; }
  __syncthreads();
  float acc[8][2] = {};
  float sq = 0.f, nm_local = 0.f;
  const float* fb = feat + (size_t)b * DD * NP;
  const float* vb = vlad + (size_t)b * DD * KC;
  for (int dc = 0; dc < DD / 4; dc += 32) {
    int dd0 = d_start + dc;
    for (int i = tid; i < 32 * 128; i += 256) {
      int r = i >> 7, c = i & 127;
      float v = fb[(size_t)(dd0 + r) * NP + n0 + c];
      As[r][c] = v;
      sq = fmaf(v, v, sq);
    }
    for (int i = tid; i < 32 * 32; i += 256) {
      int r = i >> 5, c = i & 31;
      float v = vb[(size_t)(dd0 + r) * KC + c] / piS[c];   // pi-divide inline
      Bs[r][c] = v;
      if (nt == 0) nm_local = fmaf(v, v, nm_local);        // c == tid&31 constant
    }
    __syncthreads();
    if (nt == 0 && tid < 32) {                              // gmax: per-d max over k
      float gm = -1e30f;
#pragma unroll
      for (int c = 0; c < KC; c++) gm = fmaxf(gm, Bs[tid][c]);
      gmax[(size_t)b * DD + dd0 + tid] = gm;
    }
#pragma unroll 4
    for (int kk = 0; kk < 32; kk++) {
      float ra[8], rb[2];
#pragma unroll
      for (int i = 0; i < 8; i++) ra[i] = As[kk][ty * 8 + i];
      rb[0] = Bs[kk][tx * 2]; rb[1] = Bs[kk][tx * 2 + 1];
#pragma unroll
      for (int i = 0; i < 8; i++) { acc[i][0] = fmaf(ra[i], rb[0], acc[i][0]); acc[i][1] = fmaf(ra[i], rb[1], acc[i][1]); }
    }
    __syncthreads();
  }
#pragma unroll
  for (int i = 0; i < 8; i++)
#pragma unroll
    for (int j = 0; j < 2; j++)
      atomicAdd(&costd[((size_t)b * NP + n0 + ty * 8 + i) * KC + tx * 2 + j], acc[i][j]);
  if (tid < 128) nfs[tid] = 0.f;
  __syncthreads();
  atomicAdd(&nfs[tid & 127], sq);
  if (nt == 0) atomicAdd(&nms[tid & 31], nm_local);
  __syncthreads();
  if (tid < 128) atomicAdd(&nfsq[(size_t)b * NP + n0 + tid], nfs[tid]);
  if (nt == 0 && tid < KC) atomicAdd(&nmusq[b * KC + tid], nms[tid]);
}

// ---------------- fused sinkhorn (unchanged from R7 — measured-good ~185 us)
__global__ __launch_bounds__(256) void sinkhorn_all(
    const float* __restrict__ costd, const float* __restrict__ nfsq,
    const float* __restrict__ nmusq, u64* __restrict__ G,
    const float* __restrict__ LSm, const float* __restrict__ lseArr,
    float* __restrict__ out0, unsigned* __restrict__ flags,
    float logp, float logq) {
  const float EPS = 1e-3f, IEPS = 1000.f;
  int b = blockIdx.x / NJB, j = blockIdx.x % NJB;
  int tid = threadIdx.x;
  int n = j * 256 + tid;
  __shared__ float vsh[KC];
  __shared__ float nmS[KC];
  __shared__ float vals[256][33];
  __shared__ float red[KC][9];
  __shared__ float bmS[KC];
  __shared__ float redL[4];

  if (tid < KC) nmS[tid] = fmaxf(sqrtf(nmusq[b * KC + tid]), 1e-12f);
  __syncthreads();

  float c[KC];
  {
    const float* dp = costd + ((size_t)b * NP + n) * KC;
    float nf = fmaxf(sqrtf(nfsq[(size_t)b * NP + n]), 1e-12f);
#pragma unroll
    for (int k = 0; k < KC; k++) c[k] = 2.f - 2.f * dp[k] / (nf * nmS[k]);
  }

  const int kk = tid & 31, seg = tid >> 5;
  const int r0 = seg * 32;
  float u = 0.f;

  for (int t = 1; t <= 25; t++) {
    if (t > 1) {
      if (tid < NJB) {
        const unsigned* fp = flags + ((size_t)(t - 2) * BB + b) * NJB;
        while (__hip_atomic_load(&fp[tid], __ATOMIC_RELAXED, __HIP_MEMORY_SCOPE_AGENT) == 0u)
          __builtin_amdgcn_s_sleep(1);
      }
      __syncthreads();
    }
    if (tid < KC) {
      float v = 0.f;
      if (t > 1) {
        const u64* Gp = G + (((size_t)(t - 2) * BB + b) * NJB) * KC;
        float gm[NJB], gs[NJB];
#pragma unroll
        for (int jj = 0; jj < NJB; jj++) {
          u64 raw = __hip_atomic_load(&Gp[jj * KC + tid], __ATOMIC_RELAXED, __HIP_MEMORY_SCOPE_AGENT);
          gm[jj] = __uint_as_float((unsigned)raw);
          gs[jj] = __uint_as_float((unsigned)(raw >> 32));
        }
        float m = -1e30f;
#pragma unroll
        for (int jj = 0; jj < NJB; jj++) m = fmaxf(m, gm[jj]);
        float s = 0.f;
#pragma unroll
        for (int jj = 0; jj < NJB; jj++) s += gs[jj] * expf(gm[jj] - m);
        v = EPS * logq - EPS * (m + logf(s));
      }
      vsh[tid] = v;
    }
    __syncthreads();
    float m = -1e30f;
#pragma unroll
    for (int k = 0; k < KC; k++) m = fmaxf(m, vsh[k] - c[k]);
    float s = 0.f;
#pragma unroll
    for (int k = 0; k < KC; k++) s += expf((vsh[k] - c[k] - m) * IEPS);
    u = EPS * logp - m - EPS * logf(s);
#pragma unroll
    for (int k = 0; k < KC; k++) vals[tid][k] = (u - c[k]) * IEPS;
    __syncthreads();
    {
      float lm = -1e30f;
      for (int r = 0; r < 32; r++) lm = fmaxf(lm, vals[r0 + r][kk]);
      red[kk][seg] = lm;
    }
    __syncthreads();
    if (tid < KC) {
      float bm = red[tid][0];
      for (int i2 = 1; i2 < 8; i2++) bm = fmaxf(bm, red[tid][i2]);
      bmS[tid] = bm;
    }
    __syncthreads();
    {
      float bm = bmS[kk];
      float ls = 0.f;
      for (int r = 0; r < 32; r++) ls += expf(vals[r0 + r][kk] - bm);
      red[kk][seg] = ls;
    }
    __syncthreads();
    if (tid < KC) {
      float s8 = 0.f;
      for (int i2 = 0; i2 < 8; i2++) s8 += red[tid][i2];
      u64 raw = (u64)__float_as_uint(bmS[tid]) | ((u64)__float_as_uint(s8) << 32);
      u64* Gp = G + (((size_t)(t - 1) * BB + b) * NJB + j) * KC + tid;
      __hip_atomic_store(Gp, raw, __ATOMIC_RELAXED, __HIP_MEMORY_SCOPE_AGENT);
    }
    __syncthreads();
    if (tid == 0) {
      unsigned* fl = flags + ((size_t)(t - 1) * BB + b) * NJB + j;
      __hip_atomic_store(fl, 1u, __ATOMIC_RELAXED, __HIP_MEMORY_SCOPE_AGENT);
    }
  }

  if (tid < NJB) {
    const unsigned* fp = flags + ((size_t)24 * BB + b) * NJB;
    while (__hip_atomic_load(&fp[tid], __ATOMIC_RELAXED, __HIP_MEMORY_SCOPE_AGENT) == 0u)
      __builtin_amdgcn_s_sleep(1);
  }
  __syncthreads();
  __shared__ float v25S[KC];
  if (tid < KC) {
    const u64* Gp = G + (((size_t)24 * BB + b) * NJB) * KC;
    float gm[NJB], gs[NJB];
#pragma unroll
    for (int jj = 0; jj < NJB; jj++) {
      u64 raw = __hip_atomic_load(&Gp[jj * KC + tid], __ATOMIC_RELAXED, __HIP_MEMORY_SCOPE_AGENT);
      gm[jj] = __uint_as_float((unsigned)raw);
      gs[jj] = __uint_as_float((unsigned)(raw >> 32));
    }
    float m = -1e30f;
#pragma unroll
    for (int jj = 0; jj < NJB; jj++) m = fmaxf(m, gm[jj]);
    float s = 0.f;
#pragma unroll
    for (int jj = 0; jj < NJB; jj++) s += gs[jj] * expf(gm[jj] - m);
    v25S[tid] = EPS * logq - EPS * (m + logf(s));
  }
  __syncthreads();
  float lsev = lseArr[(size_t)b * NP + n];
  float part = 0.f;
#pragma unroll
  for (int k = 0; k < KC; k++) {
    float gamma = expf((u + v25S[k] - c[k]) * IEPS);
    float logsm = LSm[((size_t)b * KC + k) * NP + n] - lsev;
    part += gamma * logsm;
  }
  part *= (float)NP;
  int lane = tid & 63, wid = tid >> 6;
  part = waveReduceSum(part);
  if (lane == 0) redL[wid] = part;
  __syncthreads();
  if (tid == 0) {
    float tt = redL[0] + redL[1] + redL[2] + redL[3];
    atomicAdd(out0, -tt / (float)(BB * NP));
  }
}

// ---------------- tiled f32 conv1x1 GEMM (projector head). BNRELU consumer-side,
// ACCST producer-side stats, PDIV per-column pi-divide (raw vlad input).
template<int BM, int BN, int BK, int TM, int TN, bool BNRELU, bool ACCST, bool PDIV>
__global__ __launch_bounds__(256) void gemm_conv(
    const float* __restrict__ W, const float* __restrict__ bias,
    const float* __restrict__ X, float* __restrict__ Y,
    const float* __restrict__ pidiv,
    const float* __restrict__ insum, const float* __restrict__ insq,
    const float* __restrict__ bng, const float* __restrict__ bnb, float cnt,
    float* __restrict__ gsum, float* __restrict__ gsq,
    int M, int K, int N) {
  __shared__ float As[BK][BM + 4];
  __shared__ float Xs[BK][BN + 4];
  __shared__ float scS[512], shS[512];
  __shared__ float piS[BN + 4];
  const int b = blockIdx.z;
  const int m0 = blockIdx.y * BM;
  const int n0 = blockIdx.x * BN;
  const int tid = threadIdx.x;
  const int tx = tid % (BN / TN);
  const int ty = tid / (BN / TN);
  if (PDIV) {
    if (tid < N) piS[tid] = fmaxf(pidiv[b * N + tid], 1e-4f);
  }
  if (BNRELU) {
    for (int c0 = tid; c0 < K; c0 += 256) {
      float mean = insum[c0] / cnt;
      float var = insq[c0] / cnt - mean * mean;
      float sc = bng[c0] / sqrtf(var + BN_EPS);
      scS[c0] = sc; shS[c0] = bnb[c0] - mean * sc;
    }
  }
  if (PDIV || BNRELU) __syncthreads();
  const float* Xb = X + (size_t)b * K * N;
  float acc[TM][TN];
#pragma unroll
  for (int i = 0; i < TM; i++)
#pragma unroll
    for (int j = 0; j < TN; j++) acc[i][j] = 0.f;

  for (int k0 = 0; k0 < K; k0 += BK) {
    for (int i = tid; i < BM * BK; i += 256) {
      int r = i / BK, c = i % BK;
      As[c][r] = W[(size_t)(m0 + r) * K + k0 + c];
    }
    for (int i = tid; i < BK * BN; i += 256) {
      int r = i / BN, c = i % BN;
      float x = Xb[(size_t)(k0 + r) * N + n0 + c];
      if (PDIV) x /= piS[n0 + c];
      if (BNRELU) x = fmaxf(fmaf(x, scS[k0 + r], shS[k0 + r]), 0.f);
      Xs[r][c] = x;
    }
    __syncthreads();
#pragma unroll 4
    for (int kk = 0; kk < BK; kk++) {
      float ra[TM], rb[TN];
#pragma unroll
      for (int i = 0; i < TM; i++) ra[i] = As[kk][ty * TM + i];
#pragma unroll
      for (int j = 0; j < TN; j++) rb[j] = Xs[kk][tx * TN + j];
#pragma unroll
      for (int i = 0; i < TM; i++)
#pragma unroll
        for (int j = 0; j < TN; j++) acc[i][j] = fmaf(ra[i], rb[j], acc[i][j]);
    }
    __syncthreads();
  }
  float* red = (float*)As;
  if (ACCST) {
    if (tid < 2 * BM) red[tid] = 0.f;
    __syncthreads();
  }
#pragma unroll
  for (int i = 0; i < TM; i++) {
    int ml = ty * TM + i;
    float bm = bias[m0 + ml];
    float ys = 0.f, yq = 0.f;
#pragma unroll
    for (int j = 0; j < TN; j++) {
      float y = acc[i][j] + bm;
      Y[((size_t)b * M + m0 + ml) * N + n0 + tx * TN + j] = y;
      ys += y; yq = fmaf(y, y, yq);
    }
    if (ACCST) {
      atomicAdd(&red[ml * 2], ys);
      atomicAdd(&red[ml * 2 + 1], yq);
    }
  }
  if (ACCST) {
    __syncthreads();
    if (tid < BM) {
      atomicAdd(&gsum[m0 + tid], red[tid * 2]);
      atomicAdd(&gsq[m0 + tid], red[tid * 2 + 1]);
    }
  }
}

// ---------------- tiny MLP gemm: one wave per output; BNRELU consumer-side,
// ACCST producer-side stats (mlp_bnstats fused).
template<bool BNRELU, bool ACCST>
__global__ __launch_bounds__(256) void mlp_gemm(
    const float* __restrict__ W, const float* __restrict__ bias,
    const float* __restrict__ in, float* __restrict__ out,
    const float* __restrict__ insum, const float* __restrict__ insq,
    const float* __restrict__ g, const float* __restrict__ beta,
    float* __restrict__ gsum, float* __restrict__ gsq, int M, int K) {
  __shared__ float scS[512], shS[512];
  int tid = threadIdx.x;
  if (BNRELU) {
    for (int c0 = tid; c0 < K; c0 += 256) {
      float mean = insum[c0] * 0.125f;           // cnt = BB = 8
      float var = insq[c0] * 0.125f - mean * mean;
      float sc = g[c0] / sqrtf(var + BN_EPS);
      scS[c0] = sc; shS[c0] = beta[c0] - mean * sc;
    }
    __syncthreads();
  }
  int gw = (blockIdx.x * 256 + tid) >> 6;
  int lane = tid & 63;
  int s = gw / M, jj = gw % M;
  const float4* ip = (const float4*)(in + (size_t)s * K);
  const float4* wp = (const float4*)(W + (size_t)jj * K);
  float acc = 0.f;
  for (int c4 = lane; c4 < (K >> 2); c4 += 64) {
    float4 x = ip[c4];
    float4 w = wp[c4];
    if (BNRELU) {
      int cb = c4 * 4;
      x.x = fmaxf(fmaf(x.x, scS[cb + 0], shS[cb + 0]), 0.f);
      x.y = fmaxf(fmaf(x.y, scS[cb + 1], shS[cb + 1]), 0.f);
      x.z = fmaxf(fmaf(x.z, scS[cb + 2], shS[cb + 2]), 0.f);
      x.w = fmaxf(fmaf(x.w, scS[cb + 3], shS[cb + 3]), 0.f);
    }
    acc += x.x * w.x + x.y * w.y + x.z * w.z + x.w * w.w;
  }
  acc = waveReduceSum(acc);
  if (lane == 0) {
    float y = acc + bias[jj];
    out[gw] = y;
    if (ACCST) { atomicAdd(&gsum[jj], y); atomicAdd(&gsq[jj], y * y); }
  }
}

// ---------------- launch ----------------
extern "C" void kernel_launch(void* const* d_in, const int* in_sizes, int n_in,
                              void* d_out, int out_size, void* d_ws, size_t ws_size,
                              hipStream_t stream) {
  const float* feat = (const float*)d_in[0];
  const float* cw1 = (const float*)d_in[1];  const float* cb1 = (const float*)d_in[2];
  const float* cg1 = (const float*)d_in[3];  const float* ct1 = (const float*)d_in[4];
  const float* cw2 = (const float*)d_in[5];  const float* cb2 = (const float*)d_in[6];
  const float* cg2 = (const float*)d_in[7];  const float* ct2 = (const float*)d_in[8];
  const float* cw3 = (const float*)d_in[9];  const float* cb3 = (const float*)d_in[10];
  const float* pw1 = (const float*)d_in[11]; const float* pb1 = (const float*)d_in[12];
  const float* pg1 = (const float*)d_in[13]; const float* pt1 = (const float*)d_in[14];
  const float* pw2 = (const float*)d_in[15]; const float* pb2 = (const float*)d_in[16];
  const float* pg2 = (const float*)d_in[17]; const float* pt2 = (const float*)d_in[18];
  const float* pw3 = (const float*)d_in[19]; const float* pb3 = (const float*)d_in[20];
  const float* mw1 = (const float*)d_in[21]; const float* mb1 = (const float*)d_in[22];
  const float* mg1 = (const float*)d_in[23]; const float* mt1 = (const float*)d_in[24];
  const float* mw2 = (const float*)d_in[25]; const float* mb2 = (const float*)d_in[26];
  const float* mg2 = (const float*)d_in[27]; const float* mt2 = (const float*)d_in[28];
  const float* mw3 = (const float*)d_in[29]; const float* mb3 = (const float*)d_in[30];
  float* out = (float*)d_out;

  // ---- workspace layout: post-GEMM2 buffers alias Y1 ----
  char* p = (char*)d_ws;
  size_t off = 0;
  auto alloc = [&](size_t bytes) { char* r = p + off; off = (off + bytes + 255) & ~(size_t)255; return r; };
  float* Y1 = (float*)alloc(67108864);   // [8][512][4096] f32
  float* Y2 = (float*)alloc(67108864);
  u16* W1H = (u16*)alloc(1048576); u16* W1M = (u16*)alloc(1048576); u16* W1L = (u16*)alloc(1048576);
  u16* W2H = (u16*)alloc(524288);  u16* W2M = (u16*)alloc(524288);  u16* W2L = (u16*)alloc(524288);
  u16* W3H = (u16*)alloc(32768);   u16* W3M = (u16*)alloc(32768);   u16* W3L = (u16*)alloc(32768);
  // BN accumulators (24 KB, zeroed by convW3_all idle blocks)
  float* BNACC = (float*)alloc(24576);
  float* GS1 = BNACC + 0,    * GQ1 = BNACC + 512;
  float* GS2 = BNACC + 1024, * GQ2 = BNACC + 1536;
  float* MSS1 = BNACC + 2048, * MSQ1 = BNACC + 2560;
  float* MSS2 = BNACC + 3072, * MSQ2 = BNACC + 3584;
  float* PS1 = BNACC + 4096, * PQ1 = BNACC + 4608;
  float* PS2 = BNACC + 5120, * PQ2 = BNACC + 5632;
  // ---- sub-arena inside Y1's region: first written AFTER GEMM2 completes ----
  char* q = (char*)Y1;
  size_t qoff = 0;
  auto qalloc = [&](size_t bytes) { char* r = q + qoff; qoff = (qoff + bytes + 255) & ~(size_t)255; return r; };
  float* LSC  = (float*)qalloc(4194304);  // [8][32][4096], written by GEMM3
  float* SCRB = (float*)qalloc(4194304);  // score
  float* LSE  = (float*)qalloc(131072);
  u64*   GBUF = (u64*)qalloc(819200);     // 25*8*16*32 u64 pairs
  float* GMAX = (float*)qalloc(32768);
  float* MH1  = (float*)qalloc(16384);
  float* MH2  = (float*)qalloc(16384);
  float* T1   = (float*)qalloc(524288);
  float* T2   = (float*)qalloc(524288);
  // contiguous memset region: PIRAW | VLAD | COSTD | NFSQ | NMUSQ | FLAGS(16KB)
  const size_t MS_BYTES = 1024 + 1048576 + 4194304 + 131072 + 1024 + 16384;
  char* MS = qalloc(MS_BYTES);
  float* PIRAW = (float*)MS;
  float* VLAD  = (float*)(MS + 1024);
  float* COSTD = (float*)(MS + 1024 + 1048576);
  float* NFSQ  = (float*)(MS + 1024 + 1048576 + 4194304);
  float* NMUSQ = (float*)(MS + 1024 + 1048576 + 4194304 + 131072);
  unsigned* FLG = (unsigned*)(MS + 1024 + 1048576 + 4194304 + 131072 + 1024);

  hipMemsetAsync(d_out, 0, sizeof(float), stream);

  float logp = logf(1.0f / NP + 1e-8f);
  float logq = logf(1.0f / KC + 1e-8f);
  const float CNT_BN = (float)(BB * NP);     // 32768 (conv-score head BN)
  const float CNT_PJ = (float)(BB * KC);     // 256   (projector BN)
  dim3 blk(256);

  // weight permute + 3-split + BNACC zeroing (one launch)
  convW3_all<<<dim3(4, 32, 3), blk, 0, stream>>>(
      cw1, W1H, W1M, W1L, cw2, W2H, W2M, W2L, cw3, W3H, W3M, W3L, BNACC);

  // GEMM1: bnstats fused into epilogue (GS1/GQ1)
  gemm_mfma3<128, 4, 4, 4, 2, false, true, false><<<dim3(128, 1, 8), blk, 0, stream>>>(
      W1H, W1M, W1L, cb1, feat, nullptr, nullptr, nullptr, nullptr, 0.f,
      Y1, 1024, 512, GS1, GQ1, nullptr, nullptr, nullptr);
  // GEMM2: consumer-side BN from GS1/GQ1; produces GS2/GQ2
  gemm_mfma3<128, 4, 4, 4, 2, true, true, false><<<dim3(128, 1, 8), blk, 0, stream>>>(
      W2H, W2M, W2L, cb2, Y1, GS1, GQ1, cg1, ct1, CNT_BN,
      Y2, 512, 512, GS2, GQ2, nullptr, nullptr, nullptr);
  // Y1 dead -> zero aliased accumulation buffers (PIRAW must precede GEMM3)
  hipMemsetAsync(MS, 0, MS_BYTES, stream);
  // GEMM3: consumer BN from GS2/GQ2 + fused softmax_pi epilogue
  gemm_mfma3<32, 1, 2, 2, 1, true, false, true><<<dim3(32, 1, 8), blk, 0, stream>>>(
      W3H, W3M, W3L, cb3, Y2, GS2, GQ2, cg2, ct2, CNT_BN,
      LSC, 512, 32, nullptr, nullptr, SCRB, LSE, PIRAW);

  // vlad (raw, undivided)
  vlad_accum<<<dim3(8, DD / 128, BB), blk, 0, stream>>>(feat, SCRB, VLAD);

  // cost dots + fused pi-divide / ||f||^2 / ||mu||^2 / gmax (vlad_fin eliminated)
  cost_accum<<<dim3(4, NP / 128, BB), blk, 0, stream>>>(
      feat, VLAD, PIRAW, COSTD, NFSQ, NMUSQ, GMAX);

  // fused sinkhorn (unchanged)
  sinkhorn_all<<<dim3(BB * NJB), blk, 0, stream>>>(
      COSTD, NFSQ, NMUSQ, GBUF, LSC, LSE, out, FLG, logp, logq);

  // predictor MLP (mlp_bnstats fused: producer atomics + consumer recompute)
  mlp_gemm<false, true><<<dim3(BB * HH / 4), blk, 0, stream>>>(
      mw1, mb1, GMAX, MH1, nullptr, nullptr, nullptr, nullptr, MSS1, MSQ1, HH, DD);
  mlp_gemm<true, true><<<dim3(BB * HH / 4), blk, 0, stream>>>(
      mw2, mb2, MH1, MH2, MSS1, MSQ1, mg1, mt1, MSS2, MSQ2, HH, HH);
  mlp_gemm<true, false><<<dim3(BB * PP / 4), blk, 0, stream>>>(
      mw3, mb3, MH2, out + 1 + BB * PP * KC, MSS2, MSQ2, mg2, mt2, nullptr, nullptr, PP, HH);

  // projector conv head (bnstats fused; pi-divide inline on raw vlad)
  gemm_conv<64, 32, 16, 4, 2, false, true, true><<<dim3(1, HH / 64, BB), blk, 0, stream>>>(
      pw1, pb1, VLAD, T1, PIRAW, nullptr, nullptr, nullptr, nullptr, 0.f, PS1, PQ1, HH, DD, KC);
  gemm_conv<64, 32, 16, 4, 2, true, true, false><<<dim3(1, HH / 64, BB), blk, 0, stream>>>(
      pw2, pb2, T1, T2, nullptr, PS1, PQ1, pg1, pt1, CNT_PJ, PS2, PQ2, HH, HH, KC);
  gemm_conv<64, 32, 16, 4, 2, true, false, false><<<dim3(1, PP / 64, BB), blk, 0, stream>>>(
      pw3, pb3, T2, out + 1, nullptr, PS2, PQ2, pg2, pt2, CNT_PJ, nullptr, nullptr, PP, HH, KC);
}

// Round 9
// 1148.707 us; speedup vs baseline: 1.0673x; 1.0673x over previous
//
#include <hip/hip_runtime.h>
#include <cmath>

#define BB 8
#define DD 1024
#define NP 4096
#define KC 32
#define HH 512
#define PP 128
#define NJB 16          // sinkhorn blocks per batch
#define BN_EPS 1e-5f
#define NSLOT 32        // BN stat accumulation slots (8 bz x 4 n-quadrant)

typedef unsigned short u16;
typedef unsigned long long u64;
typedef short s16x8 __attribute__((ext_vector_type(8)));
typedef float f32x4 __attribute__((ext_vector_type(4)));

// ---------------- wave helpers ----------------
__device__ __forceinline__ float waveReduceSum(float v) {
#pragma unroll
  for (int o = 32; o > 0; o >>= 1) v += __shfl_down(v, o, 64);
  return v;
}

// ---------------- bf16 3-way split: y = h + m + l + O(2^-24 |y|) ----------
__device__ __forceinline__ void split3(float y, short& h, short& m, short& l) {
  unsigned uy = __float_as_uint(y);
  h = (short)(uy >> 16);
  float r1 = y - __uint_as_float(uy & 0xFFFF0000u);
  unsigned um = __float_as_uint(r1);
  m = (short)(um >> 16);
  float r2 = r1 - __uint_as_float(um & 0xFFFF0000u);
  l = (short)(__float_as_uint(r2) >> 16);
}

// ---------------- W pre-permute + 3-split (+ zero BN accumulators with idle blocks)
__global__ __launch_bounds__(256) void convW3_all(
    const float* __restrict__ W1, u16* __restrict__ h1, u16* __restrict__ m1, u16* __restrict__ l1,
    const float* __restrict__ W2, u16* __restrict__ h2, u16* __restrict__ m2, u16* __restrict__ l2,
    const float* __restrict__ W3, u16* __restrict__ h3, u16* __restrict__ m3, u16* __restrict__ l3,
    float* __restrict__ zbuf) {
  int z = blockIdx.z;
  // z==2 only uses mt==0; idle blocks zero the 69632-float BN-accumulator region
  if (z == 2 && blockIdx.x >= 1) {
    int id = (blockIdx.x - 1) * 32 + blockIdx.y;   // 0..95
#pragma unroll
    for (int k2 = 0; k2 < 3; k2++) {
      int idx = k2 * 24576 + id * 256 + (int)threadIdx.x;
      if (idx < 69632) zbuf[idx] = 0.f;
    }
    return;
  }
  const float* W; u16 *hb, *mb, *lb; int K, BM, MTt, KCH;
  if (z == 0)      { W = W1; hb = h1; mb = m1; lb = l1; K = 1024; BM = 128; MTt = 4; KCH = 32; }
  else if (z == 1) { W = W2; hb = h2; mb = m2; lb = l2; K = 512;  BM = 128; MTt = 4; KCH = 16; }
  else             { W = W3; hb = h3; mb = m3; lb = l3; K = 512;  BM = 32;  MTt = 1; KCH = 16; }
  int mt = blockIdx.x, kc = blockIdx.y;
  if (mt >= MTt || kc >= KCH) return;
  const int AU = BM * 4;
  for (int u = threadIdx.x; u < AU; u += 256) {
    int q = u / BM, m = u % BM;
    const float* wp = W + (size_t)(mt * BM + m) * K + kc * 32 + q * 8;
    s16x8 hv, mv, lv;
#pragma unroll
    for (int j = 0; j < 8; j++) {
      short h, mm, l; split3(wp[j], h, mm, l);
      hv[j] = h; mv[j] = mm; lv[j] = l;
    }
    size_t ob = ((size_t)(mt * KCH + kc)) * (size_t)(BM * 32) + (size_t)u * 8;
    *(s16x8*)(hb + ob) = hv;
    *(s16x8*)(mb + ob) = mv;
    *(s16x8*)(lb + ob) = lv;
  }
}

// ---------------- bf16x3 MFMA GEMM, reg-prefetch pipelined.
// BNRELU: consumer-side BN (sums NSLOT slot-partials, computes scale/shift in-block).
// ACCST:  producer-side per-channel sum/sumsq, contention-spread:
//         shfl-reduce over cols -> plain LDS slots -> per-(bz,nh) global atomics.
// SMAX:   fused softmax-over-M epilogue (requires WM==1, BM==KC).
template<int BM, int MBLK, int MT, int NT, int WM, bool BNRELU, bool ACCST, bool SMAX>
__global__ __launch_bounds__(256) void gemm_mfma3(
    const u16* __restrict__ wh, const u16* __restrict__ wmid, const u16* __restrict__ wl,
    const float* __restrict__ bias, const float* __restrict__ X,
    const float* __restrict__ insum, const float* __restrict__ insq,
    const float* __restrict__ bng, const float* __restrict__ bnb, float cnt,
    float* __restrict__ Y, int K, int M,
    float* __restrict__ gsum, float* __restrict__ gsq,
    float* __restrict__ score, float* __restrict__ lse, float* __restrict__ piraw) {
  __shared__ s16x8 AhS[BM * 4], AmS[BM * 4], AlS[BM * 4];
  __shared__ s16x8 BhS[512], BmS[512], BlS[512];
  __shared__ float scS[512], shS[512];
  const int KCH = K / 32;
  const int tid = threadIdx.x;
  const int bz = blockIdx.z;
  int bid = blockIdx.x;
  int xs = bid & 7, rr = bid >> 3;
  int m_idx = rr % MBLK;
  int n_idx = xs + 8 * (rr / MBLK);

  const int w = tid >> 6, l = tid & 63, q = l >> 4, col = l & 15;
  const int wm = (WM == 1) ? 0 : (w >> 1);
  const int wn = (WM == 1) ? w : (w & 1);
  constexpr int NA = (BM * 4 + 255) / 256;

  if (BNRELU) {
    for (int c0 = tid; c0 < K; c0 += 256) {
      float s = 0.f, q2 = 0.f;
      for (int sl = 0; sl < NSLOT; sl++) { s += insum[sl * 512 + c0]; q2 += insq[sl * 512 + c0]; }
      float mean = s / cnt;
      float var = q2 / cnt - mean * mean;
      float sc = bng[c0] / sqrtf(var + BN_EPS);
      scS[c0] = sc; shS[c0] = bnb[c0] - mean * sc;
    }
    __syncthreads();
  }

  f32x4 acc[MT][NT];
#pragma unroll
  for (int i = 0; i < MT; i++)
#pragma unroll
    for (int j = 0; j < NT; j++) { acc[i][j][0] = 0.f; acc[i][j][1] = 0.f; acc[i][j][2] = 0.f; acc[i][j][3] = 0.f; }

  const short* Ah = (const short*)AhS;
  const short* Am = (const short*)AmS;
  const short* Al = (const short*)AlS;
  const short* Bh = (const short*)BhS;
  const short* Bm = (const short*)BmS;
  const short* Bl = (const short*)BlS;

  const float* Xb = X + (size_t)bz * (size_t)K * NP + (size_t)n_idx * 128;
  const size_t abase = (size_t)m_idx * KCH * (size_t)(BM * 32);

  s16x8 rAh[NA], rAm[NA], rAl[NA];
  float rB[2][8];

  {
    const s16x8* awh = (const s16x8*)(wh + abase);
    const s16x8* awm = (const s16x8*)(wmid + abase);
    const s16x8* awl = (const s16x8*)(wl + abase);
#pragma unroll
    for (int t = 0; t < NA; t++) {
      int u = tid + t * 256;
      if (u < BM * 4) { rAh[t] = awh[u]; rAm[t] = awm[u]; rAl[t] = awl[u]; }
    }
#pragma unroll
    for (int t = 0; t < 2; t++) {
      int u = tid + t * 256;
      int qq = u >> 7, n = u & 127;
      const float* fp = Xb + (size_t)(qq * 8) * NP + n;
#pragma unroll
      for (int j = 0; j < 8; j++) {
        float y = fp[(size_t)j * NP];
        if (BNRELU) y = fmaxf(fmaf(y, scS[qq * 8 + j], shS[qq * 8 + j]), 0.f);
        rB[t][j] = y;
      }
    }
  }

  for (int kc = 0; kc < KCH; kc++) {
#pragma unroll
    for (int t = 0; t < NA; t++) {
      int u = tid + t * 256;
      if (u < BM * 4) { AhS[u] = rAh[t]; AmS[u] = rAm[t]; AlS[u] = rAl[t]; }
    }
#pragma unroll
    for (int t = 0; t < 2; t++) {
      int u = tid + t * 256;
      s16x8 hv, mv, lv;
#pragma unroll
      for (int j = 0; j < 8; j++) {
        short h, mm, ll; split3(rB[t][j], h, mm, ll);
        hv[j] = h; mv[j] = mm; lv[j] = ll;
      }
      BhS[u] = hv; BmS[u] = mv; BlS[u] = lv;
    }
    __syncthreads();

    if (kc + 1 < KCH) {
      size_t ab = abase + (size_t)(kc + 1) * (size_t)(BM * 32);
      const s16x8* awh = (const s16x8*)(wh + ab);
      const s16x8* awm = (const s16x8*)(wmid + ab);
      const s16x8* awl = (const s16x8*)(wl + ab);
#pragma unroll
      for (int t = 0; t < NA; t++) {
        int u = tid + t * 256;
        if (u < BM * 4) { rAh[t] = awh[u]; rAm[t] = awm[u]; rAl[t] = awl[u]; }
      }
      const int kp = (kc + 1) * 32;
#pragma unroll
      for (int t = 0; t < 2; t++) {
        int u = tid + t * 256;
        int qq = u >> 7, n = u & 127;
        const float* fp = Xb + (size_t)(kp + qq * 8) * NP + n;
#pragma unroll
        for (int j = 0; j < 8; j++) {
          float y = fp[(size_t)j * NP];
          if (BNRELU) y = fmaxf(fmaf(y, scS[kp + qq * 8 + j], shS[kp + qq * 8 + j]), 0.f);
          rB[t][j] = y;
        }
      }
    }

    s16x8 ah[MT], am[MT], al[MT];
#pragma unroll
    for (int i = 0; i < MT; i++) {
      int off = (q * BM + wm * (MT * 16) + i * 16 + col) * 8;
      ah[i] = *(const s16x8*)(Ah + off);
      am[i] = *(const s16x8*)(Am + off);
      al[i] = *(const s16x8*)(Al + off);
    }
    __builtin_amdgcn_s_setprio(1);
#pragma unroll
    for (int j = 0; j < NT; j++) {
      int offb = (q * 128 + wn * (NT * 16) + j * 16 + col) * 8;
      s16x8 bh = *(const s16x8*)(Bh + offb);
      s16x8 bm = *(const s16x8*)(Bm + offb);
      s16x8 bl = *(const s16x8*)(Bl + offb);
#pragma unroll
      for (int i = 0; i < MT; i++) {
        acc[i][j] = __builtin_amdgcn_mfma_f32_16x16x32_bf16(ah[i], bh, acc[i][j], 0, 0, 0);
        acc[i][j] = __builtin_amdgcn_mfma_f32_16x16x32_bf16(ah[i], bm, acc[i][j], 0, 0, 0);
        acc[i][j] = __builtin_amdgcn_mfma_f32_16x16x32_bf16(am[i], bh, acc[i][j], 0, 0, 0);
        acc[i][j] = __builtin_amdgcn_mfma_f32_16x16x32_bf16(ah[i], bl, acc[i][j], 0, 0, 0);
        acc[i][j] = __builtin_amdgcn_mfma_f32_16x16x32_bf16(am[i], bm, acc[i][j], 0, 0, 0);
        acc[i][j] = __builtin_amdgcn_mfma_f32_16x16x32_bf16(al[i], bh, acc[i][j], 0, 0, 0);
      }
    }
    __builtin_amdgcn_s_setprio(0);
    __syncthreads();
  }

  if (!SMAX) {
    // ---- store + contention-free stats: shfl-reduce cols -> plain LDS -> slotted atomics
    float* red = (float*)AhS;   // [BM][4]: (wn0_ys, wn0_yq, wn1_ys, wn1_yq); K-loop ended in barrier
#pragma unroll
    for (int i = 0; i < MT; i++) {
#pragma unroll
      for (int r = 0; r < 4; r++) {
        int ml = wm * (MT * 16) + i * 16 + q * 4 + r;
        int m = m_idx * BM + ml;
        float bv = bias[m];
        float ys = 0.f, yq = 0.f;
#pragma unroll
        for (int j = 0; j < NT; j++) {
          int n = n_idx * 128 + wn * (NT * 16) + j * 16 + col;
          float y = acc[i][j][r] + bv;
          Y[((size_t)bz * M + m) * 4096 + n] = y;
          ys += y; yq = fmaf(y, y, yq);
        }
        if (ACCST) {
#pragma unroll
          for (int o = 1; o < 16; o <<= 1) { ys += __shfl_xor(ys, o, 64); yq += __shfl_xor(yq, o, 64); }
          if (col == 0) { red[ml * 4 + wn * 2] = ys; red[ml * 4 + wn * 2 + 1] = yq; }
        }
      }
    }
    if (ACCST) {
      __syncthreads();
      if (tid < BM) {
        int slot = bz * 4 + (rr / MBLK);   // 32 slots: 8-way contention per address
        atomicAdd(&gsum[slot * 512 + m_idx * BM + tid], red[tid * 4] + red[tid * 4 + 2]);
        atomicAdd(&gsq [slot * 512 + m_idx * BM + tid], red[tid * 4 + 1] + red[tid * 4 + 3]);
      }
    }
  } else {
    // ---- fused softmax over M (=KC) per column (softmax_pi replacement).
    float yv[MT][NT][4];
#pragma unroll
    for (int i = 0; i < MT; i++) {
#pragma unroll
      for (int r = 0; r < 4; r++) {
        int m = i * 16 + q * 4 + r;
        float bv = bias[m];
#pragma unroll
        for (int j = 0; j < NT; j++) {
          int n = n_idx * 128 + wn * (NT * 16) + j * 16 + col;
          float y = acc[i][j][r] + bv;
          Y[((size_t)bz * M + m) * 4096 + n] = y;
          yv[i][j][r] = y;
        }
      }
    }
    float* redP = (float*)AhS;
    if (tid < KC) redP[tid] = 0.f;
    __syncthreads();
    float pl[MT][4];
#pragma unroll
    for (int i = 0; i < MT; i++)
#pragma unroll
      for (int r = 0; r < 4; r++) pl[i][r] = 0.f;
#pragma unroll
    for (int j = 0; j < NT; j++) {
      float mx = -1e30f;
#pragma unroll
      for (int i = 0; i < MT; i++)
#pragma unroll
        for (int r = 0; r < 4; r++) mx = fmaxf(mx, yv[i][j][r]);
      mx = fmaxf(mx, __shfl_xor(mx, 16, 64));
      mx = fmaxf(mx, __shfl_xor(mx, 32, 64));
      float e[MT][4]; float s = 0.f;
#pragma unroll
      for (int i = 0; i < MT; i++)
#pragma unroll
        for (int r = 0; r < 4; r++) { e[i][r] = expf(yv[i][j][r] - mx); s += e[i][r]; }
      s += __shfl_xor(s, 16, 64);
      s += __shfl_xor(s, 32, 64);
      float inv = 1.f / s;
      int n = n_idx * 128 + wn * (NT * 16) + j * 16 + col;
#pragma unroll
      for (int i = 0; i < MT; i++)
#pragma unroll
        for (int r = 0; r < 4; r++) {
          float sv = e[i][r] * inv;
          int m = i * 16 + q * 4 + r;
          score[((size_t)bz * KC + m) * NP + n] = sv;
          pl[i][r] += sv;
        }
      if ((tid & 48) == 0) lse[(size_t)bz * NP + n] = mx + logf(s);
    }
#pragma unroll
    for (int i = 0; i < MT; i++)
#pragma unroll
      for (int r = 0; r < 4; r++) atomicAdd(&redP[i * 16 + q * 4 + r], pl[i][r]);
    __syncthreads();
    if (tid < KC) atomicAdd(&piraw[bz * KC + tid], redP[tid]);
  }
}

// ---------------- vlad accumulation (split over n, atomic) — RAW (undivided) vlad
__global__ __launch_bounds__(256) void vlad_accum(
    const float* __restrict__ feat, const float* __restrict__ score, float* __restrict__ vlad) {
  const int SPLIT_LEN = NP / 8;
  int sp = blockIdx.x, dt = blockIdx.y, b = blockIdx.z;
  int d0 = dt * 128;
  int n_start = sp * SPLIT_LEN;
  __shared__ float As[32][132];
  __shared__ float Bs[32][36];
  int tid = threadIdx.x;
  int tx = tid % 16;
  int ty = tid / 16;
  float acc[8][2] = {};
  const float* fb = feat + (size_t)b * DD * NP;
  const float* sb = score + (size_t)b * KC * NP;
  for (int nc = 0; nc < SPLIT_LEN; nc += 32) {
    int n0 = n_start + nc;
    for (int i = tid; i < 128 * 32; i += 256) {
      int r = i >> 5, c = i & 31;
      As[c][r] = fb[(size_t)(d0 + r) * NP + n0 + c];
    }
    for (int i = tid; i < 32 * 32; i += 256) {
      int r = i >> 5, c = i & 31;
      Bs[c][r] = sb[(size_t)r * NP + n0 + c];
    }
    __syncthreads();
#pragma unroll 4
    for (int kk = 0; kk < 32; kk++) {
      float ra[8], rb[2];
#pragma unroll
      for (int i = 0; i < 8; i++) ra[i] = As[kk][ty * 8 + i];
      rb[0] = Bs[kk][tx * 2]; rb[1] = Bs[kk][tx * 2 + 1];
#pragma unroll
      for (int i = 0; i < 8; i++) { acc[i][0] = fmaf(ra[i], rb[0], acc[i][0]); acc[i][1] = fmaf(ra[i], rb[1], acc[i][1]); }
    }
    __syncthreads();
  }
#pragma unroll
  for (int i = 0; i < 8; i++)
#pragma unroll
    for (int j = 0; j < 2; j++)
      atomicAdd(&vlad[((size_t)b * DD + d0 + ty * 8 + i) * KC + tx * 2 + j], acc[i][j]);
}

// ---------------- cost dot accumulation + fused: pi-divide (vlad_fin), ||f_n||^2,
// ||mu_k||^2 partials, and gmax (per-d max over k) from nt==0 blocks.
__global__ __launch_bounds__(256) void cost_accum(
    const float* __restrict__ feat, const float* __restrict__ vlad,
    const float* __restrict__ piraw, float* __restrict__ costd,
    float* __restrict__ nfsq, float* __restrict__ nmusq, float* __restrict__ gmax) {
  int sp = blockIdx.x, nt = blockIdx.y, b = blockIdx.z;
  int n0 = nt * 128;
  int d_start = sp * (DD / 4);
  __shared__ float As[32][132];
  __shared__ float Bs[32][36];
  __shared__ float nfs[128];
  __shared__ float piS[KC];
  __shared__ float nms[KC];
  int tid = threadIdx.x;
  int tx = tid % 16;
  int ty = tid / 16;
  if (tid < KC) { piS[tid] = fmaxf(piraw[b * KC + tid], 1e-4f); nms[tid] = 0.f; }
  __syncthreads();
  float acc[8][2] = {};
  float sq = 0.f, nm_local = 0.f;
  const float* fb = feat + (size_t)b * DD * NP;
  const float* vb = vlad + (size_t)b * DD * KC;
  for (int dc = 0; dc < DD / 4; dc += 32) {
    int dd0 = d_start + dc;
    for (int i = tid; i < 32 * 128; i += 256) {
      int r = i >> 7, c = i & 127;
      float v = fb[(size_t)(dd0 + r) * NP + n0 + c];
      As[r][c] = v;
      sq = fmaf(v, v, sq);
    }
    for (int i = tid; i < 32 * 32; i += 256) {
      int r = i >> 5, c = i & 31;
      float v = vb[(size_t)(dd0 + r) * KC + c] / piS[c];   // pi-divide inline
      Bs[r][c] = v;
      if (nt == 0) nm_local = fmaf(v, v, nm_local);        // c == tid&31 constant
    }
    __syncthreads();
    if (nt == 0 && tid < 32) {                              // gmax: per-d max over k
      float gm = -1e30f;
#pragma unroll
      for (int c = 0; c < KC; c++) gm = fmaxf(gm, Bs[tid][c]);
      gmax[(size_t)b * DD + dd0 + tid] = gm;
    }
#pragma unroll 4
    for (int kk = 0; kk < 32; kk++) {
      float ra[8], rb[2];
#pragma unroll
      for (int i = 0; i < 8; i++) ra[i] = As[kk][ty * 8 + i];
      rb[0] = Bs[kk][tx * 2]; rb[1] = Bs[kk][tx * 2 + 1];
#pragma unroll
      for (int i = 0; i < 8; i++) { acc[i][0] = fmaf(ra[i], rb[0], acc[i][0]); acc[i][1] = fmaf(ra[i], rb[1], acc[i][1]); }
    }
    __syncthreads();
  }
#pragma unroll
  for (int i = 0; i < 8; i++)
#pragma unroll
    for (int j = 0; j < 2; j++)
      atomicAdd(&costd[((size_t)b * NP + n0 + ty * 8 + i) * KC + tx * 2 + j], acc[i][j]);
  if (tid < 128) nfs[tid] = 0.f;
  __syncthreads();
  atomicAdd(&nfs[tid & 127], sq);
  if (nt == 0) atomicAdd(&nms[tid & 31], nm_local);
  __syncthreads();
  if (tid < 128) atomicAdd(&nfsq[(size_t)b * NP + n0 + tid], nfs[tid]);
  if (nt == 0 && tid < KC) atomicAdd(&nmusq[b * KC + tid], nms[tid]);
}

// ---------------- fused sinkhorn (unchanged — measured ~185 us)
__global__ __launch_bounds__(256) void sinkhorn_all(
    const float* __restrict__ costd, const float* __restrict__ nfsq,
    const float* __restrict__ nmusq, u64* __restrict__ G,
    const float* __restrict__ LSm, const float* __restrict__ lseArr,
    float* __restrict__ out0, unsigned* __restrict__ flags,
    float logp, float logq) {
  const float EPS = 1e-3f, IEPS = 1000.f;
  int b = blockIdx.x / NJB, j = blockIdx.x % NJB;
  int tid = threadIdx.x;
  int n = j * 256 + tid;
  __shared__ float vsh[KC];
  __shared__ float nmS[KC];
  __shared__ float vals[256][33];
  __shared__ float red[KC][9];
  __shared__ float bmS[KC];
  __shared__ float redL[4];

  if (tid < KC) nmS[tid] = fmaxf(sqrtf(nmusq[b * KC + tid]), 1e-12f);
  __syncthreads();

  float c[KC];
  {
    const float* dp = costd + ((size_t)b * NP + n) * KC;
    float nf = fmaxf(sqrtf(nfsq[(size_t)b * NP + n]), 1e-12f);
#pragma unroll
    for (int k = 0; k < KC; k++) c[k] = 2.f - 2.f * dp[k] / (nf * nmS[k]);
  }

  const int kk = tid & 31, seg = tid >> 5;
  const int r0 = seg * 32;
  float u = 0.f;

  for (int t = 1; t <= 25; t++) {
    if (t > 1) {
      if (tid < NJB) {
        const unsigned* fp = flags + ((size_t)(t - 2) * BB + b) * NJB;
        while (__hip_atomic_load(&fp[tid], __ATOMIC_RELAXED, __HIP_MEMORY_SCOPE_AGENT) == 0u)
          __builtin_amdgcn_s_sleep(1);
      }
      __syncthreads();
    }
    if (tid < KC) {
      float v = 0.f;
      if (t > 1) {
        const u64* Gp = G + (((size_t)(t - 2) * BB + b) * NJB) * KC;
        float gm[NJB], gs[NJB];
#pragma unroll
        for (int jj = 0; jj < NJB; jj++) {
          u64 raw = __hip_atomic_load(&Gp[jj * KC + tid], __ATOMIC_RELAXED, __HIP_MEMORY_SCOPE_AGENT);
          gm[jj] = __uint_as_float((unsigned)raw);
          gs[jj] = __uint_as_float((unsigned)(raw >> 32));
        }
        float m = -1e30f;
#pragma unroll
        for (int jj = 0; jj < NJB; jj++) m = fmaxf(m, gm[jj]);
        float s = 0.f;
#pragma unroll
        for (int jj = 0; jj < NJB; jj++) s += gs[jj] * expf(gm[jj] - m);
        v = EPS * logq - EPS * (m + logf(s));
      }
      vsh[tid] = v;
    }
    __syncthreads();
    float m = -1e30f;
#pragma unroll
    for (int k = 0; k < KC; k++) m = fmaxf(m, vsh[k] - c[k]);
    float s = 0.f;
#pragma unroll
    for (int k = 0; k < KC; k++) s += expf((vsh[k] - c[k] - m) * IEPS);
    u = EPS * logp - m - EPS * logf(s);
#pragma unroll
    for (int k = 0; k < KC; k++) vals[tid][k] = (u - c[k]) * IEPS;
    __syncthreads();
    {
      float lm = -1e30f;
      for (int r = 0; r < 32; r++) lm = fmaxf(lm, vals[r0 + r][kk]);
      red[kk][seg] = lm;
    }
    __syncthreads();
    if (tid < KC) {
      float bm = red[tid][0];
      for (int i2 = 1; i2 < 8; i2++) bm = fmaxf(bm, red[tid][i2]);
      bmS[tid] = bm;
    }
    __syncthreads();
    {
      float bm = bmS[kk];
      float ls = 0.f;
      for (int r = 0; r < 32; r++) ls += expf(vals[r0 + r][kk] - bm);
      red[kk][seg] = ls;
    }
    __syncthreads();
    if (tid < KC) {
      float s8 = 0.f;
      for (int i2 = 0; i2 < 8; i2++) s8 += red[tid][i2];
      u64 raw = (u64)__float_as_uint(bmS[tid]) | ((u64)__float_as_uint(s8) << 32);
      u64* Gp = G + (((size_t)(t - 1) * BB + b) * NJB + j) * KC + tid;
      __hip_atomic_store(Gp, raw, __ATOMIC_RELAXED, __HIP_MEMORY_SCOPE_AGENT);
    }
    __syncthreads();
    if (tid == 0) {
      unsigned* fl = flags + ((size_t)(t - 1) * BB + b) * NJB + j;
      __hip_atomic_store(fl, 1u, __ATOMIC_RELAXED, __HIP_MEMORY_SCOPE_AGENT);
    }
  }

  if (tid < NJB) {
    const unsigned* fp = flags + ((size_t)24 * BB + b) * NJB;
    while (__hip_atomic_load(&fp[tid], __ATOMIC_RELAXED, __HIP_MEMORY_SCOPE_AGENT) == 0u)
      __builtin_amdgcn_s_sleep(1);
  }
  __syncthreads();
  __shared__ float v25S[KC];
  if (tid < KC) {
    const u64* Gp = G + (((size_t)24 * BB + b) * NJB) * KC;
    float gm[NJB], gs[NJB];
#pragma unroll
    for (int jj = 0; jj < NJB; jj++) {
      u64 raw = __hip_atomic_load(&Gp[jj * KC + tid], __ATOMIC_RELAXED, __HIP_MEMORY_SCOPE_AGENT);
      gm[jj] = __uint_as_float((unsigned)raw);
      gs[jj] = __uint_as_float((unsigned)(raw >> 32));
    }
    float m = -1e30f;
#pragma unroll
    for (int jj = 0; jj < NJB; jj++) m = fmaxf(m, gm[jj]);
    float s = 0.f;
#pragma unroll
    for (int jj = 0; jj < NJB; jj++) s += gs[jj] * expf(gm[jj] - m);
    v25S[tid] = EPS * logq - EPS * (m + logf(s));
  }
  __syncthreads();
  float lsev = lseArr[(size_t)b * NP + n];
  float part = 0.f;
#pragma unroll
  for (int k = 0; k < KC; k++) {
    float gamma = expf((u + v25S[k] - c[k]) * IEPS);
    float logsm = LSm[((size_t)b * KC + k) * NP + n] - lsev;
    part += gamma * logsm;
  }
  part *= (float)NP;
  int lane = tid & 63, wid = tid >> 6;
  part = waveReduceSum(part);
  if (lane == 0) redL[wid] = part;
  __syncthreads();
  if (tid == 0) {
    float tt = redL[0] + redL[1] + redL[2] + redL[3];
    atomicAdd(out0, -tt / (float)(BB * NP));
  }
}

// ---------------- tiled f32 conv1x1 GEMM (projector head). BNRELU consumer-side
// (single-slot stats), ACCST producer-side, PDIV per-column pi-divide.
template<int BM, int BN, int BK, int TM, int TN, bool BNRELU, bool ACCST, bool PDIV>
__global__ __launch_bounds__(256) void gemm_conv(
    const float* __restrict__ W, const float* __restrict__ bias,
    const float* __restrict__ X, float* __restrict__ Y,
    const float* __restrict__ pidiv,
    const float* __restrict__ insum, const float* __restrict__ insq,
    const float* __restrict__ bng, const float* __restrict__ bnb, float cnt,
    float* __restrict__ gsum, float* __restrict__ gsq,
    int M, int K, int N) {
  __shared__ float As[BK][BM + 4];
  __shared__ float Xs[BK][BN + 4];
  __shared__ float scS[512], shS[512];
  __shared__ float piS[BN + 4];
  const int b = blockIdx.z;
  const int m0 = blockIdx.y * BM;
  const int n0 = blockIdx.x * BN;
  const int tid = threadIdx.x;
  const int tx = tid % (BN / TN);
  const int ty = tid / (BN / TN);
  if (PDIV) {
    if (tid < N) piS[tid] = fmaxf(pidiv[b * N + tid], 1e-4f);
  }
  if (BNRELU) {
    for (int c0 = tid; c0 < K; c0 += 256) {
      float mean = insum[c0] / cnt;
      float var = insq[c0] / cnt - mean * mean;
      float sc = bng[c0] / sqrtf(var + BN_EPS);
      scS[c0] = sc; shS[c0] = bnb[c0] - mean * sc;
    }
  }
  if (PDIV || BNRELU) __syncthreads();
  const float* Xb = X + (size_t)b * K * N;
  float acc[TM][TN];
#pragma unroll
  for (int i = 0; i < TM; i++)
#pragma unroll
    for (int j = 0; j < TN; j++) acc[i][j] = 0.f;

  for (int k0 = 0; k0 < K; k0 += BK) {
    for (int i = tid; i < BM * BK; i += 256) {
      int r = i / BK, c = i % BK;
      As[c][r] = W[(size_t)(m0 + r) * K + k0 + c];
    }
    for (int i = tid; i < BK * BN; i += 256) {
      int r = i / BN, c = i % BN;
      float x = Xb[(size_t)(k0 + r) * N + n0 + c];
      if (PDIV) x /= piS[n0 + c];
      if (BNRELU) x = fmaxf(fmaf(x, scS[k0 + r], shS[k0 + r]), 0.f);
      Xs[r][c] = x;
    }
    __syncthreads();
#pragma unroll 4
    for (int kk = 0; kk < BK; kk++) {
      float ra[TM], rb[TN];
#pragma unroll
      for (int i = 0; i < TM; i++) ra[i] = As[kk][ty * TM + i];
#pragma unroll
      for (int j = 0; j < TN; j++) rb[j] = Xs[kk][tx * TN + j];
#pragma unroll
      for (int i = 0; i < TM; i++)
#pragma unroll
        for (int j = 0; j < TN; j++) acc[i][j] = fmaf(ra[i], rb[j], acc[i][j]);
    }
    __syncthreads();
  }
  float* red = (float*)As;
  if (ACCST) {
    if (tid < 2 * BM) red[tid] = 0.f;
    __syncthreads();
  }
#pragma unroll
  for (int i = 0; i < TM; i++) {
    int ml = ty * TM + i;
    float bm = bias[m0 + ml];
    float ys = 0.f, yq = 0.f;
#pragma unroll
    for (int j = 0; j < TN; j++) {
      float y = acc[i][j] + bm;
      Y[((size_t)b * M + m0 + ml) * N + n0 + tx * TN + j] = y;
      ys += y; yq = fmaf(y, y, yq);
    }
    if (ACCST) {
      atomicAdd(&red[ml * 2], ys);
      atomicAdd(&red[ml * 2 + 1], yq);
    }
  }
  if (ACCST) {
    __syncthreads();
    if (tid < BM) {
      atomicAdd(&gsum[m0 + tid], red[tid * 2]);
      atomicAdd(&gsq[m0 + tid], red[tid * 2 + 1]);
    }
  }
}

// ---------------- tiny MLP gemm: one wave per output; BNRELU consumer-side,
// ACCST producer-side stats (mlp_bnstats fused).
template<bool BNRELU, bool ACCST>
__global__ __launch_bounds__(256) void mlp_gemm(
    const float* __restrict__ W, const float* __restrict__ bias,
    const float* __restrict__ in, float* __restrict__ out,
    const float* __restrict__ insum, const float* __restrict__ insq,
    const float* __restrict__ g, const float* __restrict__ beta,
    float* __restrict__ gsum, float* __restrict__ gsq, int M, int K) {
  __shared__ float scS[512], shS[512];
  int tid = threadIdx.x;
  if (BNRELU) {
    for (int c0 = tid; c0 < K; c0 += 256) {
      float mean = insum[c0] * 0.125f;           // cnt = BB = 8
      float var = insq[c0] * 0.125f - mean * mean;
      float sc = g[c0] / sqrtf(var + BN_EPS);
      scS[c0] = sc; shS[c0] = beta[c0] - mean * sc;
    }
    __syncthreads();
  }
  int gw = (blockIdx.x * 256 + tid) >> 6;
  int lane = tid & 63;
  int s = gw / M, jj = gw % M;
  const float4* ip = (const float4*)(in + (size_t)s * K);
  const float4* wp = (const float4*)(W + (size_t)jj * K);
  float acc = 0.f;
  for (int c4 = lane; c4 < (K >> 2); c4 += 64) {
    float4 x = ip[c4];
    float4 w = wp[c4];
    if (BNRELU) {
      int cb = c4 * 4;
      x.x = fmaxf(fmaf(x.x, scS[cb + 0], shS[cb + 0]), 0.f);
      x.y = fmaxf(fmaf(x.y, scS[cb + 1], shS[cb + 1]), 0.f);
      x.z = fmaxf(fmaf(x.z, scS[cb + 2], shS[cb + 2]), 0.f);
      x.w = fmaxf(fmaf(x.w, scS[cb + 3], shS[cb + 3]), 0.f);
    }
    acc += x.x * w.x + x.y * w.y + x.z * w.z + x.w * w.w;
  }
  acc = waveReduceSum(acc);
  if (lane == 0) {
    float y = acc + bias[jj];
    out[gw] = y;
    if (ACCST) { atomicAdd(&gsum[jj], y); atomicAdd(&gsq[jj], y * y); }
  }
}

// ---------------- launch ----------------
extern "C" void kernel_launch(void* const* d_in, const int* in_sizes, int n_in,
                              void* d_out, int out_size, void* d_ws, size_t ws_size,
                              hipStream_t stream) {
  const float* feat = (const float*)d_in[0];
  const float* cw1 = (const float*)d_in[1];  const float* cb1 = (const float*)d_in[2];
  const float* cg1 = (const float*)d_in[3];  const float* ct1 = (const float*)d_in[4];
  const float* cw2 = (const float*)d_in[5];  const float* cb2 = (const float*)d_in[6];
  const float* cg2 = (const float*)d_in[7];  const float* ct2 = (const float*)d_in[8];
  const float* cw3 = (const float*)d_in[9];  const float* cb3 = (const float*)d_in[10];
  const float* pw1 = (const float*)d_in[11]; const float* pb1 = (const float*)d_in[12];
  const float* pg1 = (const float*)d_in[13]; const float* pt1 = (const float*)d_in[14];
  const float* pw2 = (const float*)d_in[15]; const float* pb2 = (const float*)d_in[16];
  const float* pg2 = (const float*)d_in[17]; const float* pt2 = (const float*)d_in[18];
  const float* pw3 = (const float*)d_in[19]; const float* pb3 = (const float*)d_in[20];
  const float* mw1 = (const float*)d_in[21]; const float* mb1 = (const float*)d_in[22];
  const float* mg1 = (const float*)d_in[23]; const float* mt1 = (const float*)d_in[24];
  const float* mw2 = (const float*)d_in[25]; const float* mb2 = (const float*)d_in[26];
  const float* mg2 = (const float*)d_in[27]; const float* mt2 = (const float*)d_in[28];
  const float* mw3 = (const float*)d_in[29]; const float* mb3 = (const float*)d_in[30];
  float* out = (float*)d_out;

  // ---- workspace layout: post-GEMM2 buffers alias Y1 ----
  char* p = (char*)d_ws;
  size_t off = 0;
  auto alloc = [&](size_t bytes) { char* r = p + off; off = (off + bytes + 255) & ~(size_t)255; return r; };
  float* Y1 = (float*)alloc(67108864);   // [8][512][4096] f32
  float* Y2 = (float*)alloc(67108864);
  u16* W1H = (u16*)alloc(1048576); u16* W1M = (u16*)alloc(1048576); u16* W1L = (u16*)alloc(1048576);
  u16* W2H = (u16*)alloc(524288);  u16* W2M = (u16*)alloc(524288);  u16* W2L = (u16*)alloc(524288);
  u16* W3H = (u16*)alloc(32768);   u16* W3M = (u16*)alloc(32768);   u16* W3L = (u16*)alloc(32768);
  // BN accumulators: GS1/GQ1/GS2/GQ2 are 32-slot (8 bz x 4 nh) spread arrays;
  // 69632 floats total, zeroed by convW3_all idle blocks
  float* BNACC = (float*)alloc(278528);
  float* GS1 = BNACC + 0;      float* GQ1 = BNACC + 16384;
  float* GS2 = BNACC + 32768;  float* GQ2 = BNACC + 49152;
  float* MSS1 = BNACC + 65536; float* MSQ1 = BNACC + 66048;
  float* MSS2 = BNACC + 66560; float* MSQ2 = BNACC + 67072;
  float* PS1 = BNACC + 67584;  float* PQ1 = BNACC + 68096;
  float* PS2 = BNACC + 68608;  float* PQ2 = BNACC + 69120;
  // ---- sub-arena inside Y1's region: first written AFTER GEMM2 completes ----
  char* q = (char*)Y1;
  size_t qoff = 0;
  auto qalloc = [&](size_t bytes) { char* r = q + qoff; qoff = (qoff + bytes + 255) & ~(size_t)255; return r; };
  float* LSC  = (float*)qalloc(4194304);  // [8][32][4096], written by GEMM3
  float* SCRB = (float*)qalloc(4194304);  // score
  float* LSE  = (float*)qalloc(131072);
  u64*   GBUF = (u64*)qalloc(819200);     // 25*8*16*32 u64 pairs
  float* GMAX = (float*)qalloc(32768);
  float* MH1  = (float*)qalloc(16384);
  float* MH2  = (float*)qalloc(16384);
  float* T1   = (float*)qalloc(524288);
  float* T2   = (float*)qalloc(524288);
  // contiguous memset region: PIRAW | VLAD | COSTD | NFSQ | NMUSQ | FLAGS(16KB)
  const size_t MS_BYTES = 1024 + 1048576 + 4194304 + 131072 + 1024 + 16384;
  char* MS = qalloc(MS_BYTES);
  float* PIRAW = (float*)MS;
  float* VLAD  = (float*)(MS + 1024);
  float* COSTD = (float*)(MS + 1024 + 1048576);
  float* NFSQ  = (float*)(MS + 1024 + 1048576 + 4194304);
  float* NMUSQ = (float*)(MS + 1024 + 1048576 + 4194304 + 131072);
  unsigned* FLG = (unsigned*)(MS + 1024 + 1048576 + 4194304 + 131072 + 1024);

  hipMemsetAsync(d_out, 0, sizeof(float), stream);

  float logp = logf(1.0f / NP + 1e-8f);
  float logq = logf(1.0f / KC + 1e-8f);
  const float CNT_BN = (float)(BB * NP);     // 32768 (conv-score head BN)
  const float CNT_PJ = (float)(BB * KC);     // 256   (projector BN)
  dim3 blk(256);

  // weight permute + 3-split + BNACC zeroing (one launch)
  convW3_all<<<dim3(4, 32, 3), blk, 0, stream>>>(
      cw1, W1H, W1M, W1L, cw2, W2H, W2M, W2L, cw3, W3H, W3M, W3L, BNACC);

  // GEMM1: bnstats fused (shfl-reduce + 32-slot spread atomics)
  gemm_mfma3<128, 4, 4, 4, 2, false, true, false><<<dim3(128, 1, 8), blk, 0, stream>>>(
      W1H, W1M, W1L, cb1, feat, nullptr, nullptr, nullptr, nullptr, 0.f,
      Y1, 1024, 512, GS1, GQ1, nullptr, nullptr, nullptr);
  // GEMM2: consumer-side BN (sums 32 slots); produces GS2/GQ2
  gemm_mfma3<128, 4, 4, 4, 2, true, true, false><<<dim3(128, 1, 8), blk, 0, stream>>>(
      W2H, W2M, W2L, cb2, Y1, GS1, GQ1, cg1, ct1, CNT_BN,
      Y2, 512, 512, GS2, GQ2, nullptr, nullptr, nullptr);
  // Y1 dead -> zero aliased accumulation buffers (PIRAW must precede GEMM3)
  hipMemsetAsync(MS, 0, MS_BYTES, stream);
  // GEMM3: consumer BN from GS2/GQ2 + fused softmax_pi epilogue
  gemm_mfma3<32, 1, 2, 2, 1, true, false, true><<<dim3(32, 1, 8), blk, 0, stream>>>(
      W3H, W3M, W3L, cb3, Y2, GS2, GQ2, cg2, ct2, CNT_BN,
      LSC, 512, 32, nullptr, nullptr, SCRB, LSE, PIRAW);

  // vlad (raw, undivided)
  vlad_accum<<<dim3(8, DD / 128, BB), blk, 0, stream>>>(feat, SCRB, VLAD);

  // cost dots + fused pi-divide / ||f||^2 / ||mu||^2 / gmax (vlad_fin eliminated)
  cost_accum<<<dim3(4, NP / 128, BB), blk, 0, stream>>>(
      feat, VLAD, PIRAW, COSTD, NFSQ, NMUSQ, GMAX);

  // fused sinkhorn (unchanged)
  sinkhorn_all<<<dim3(BB * NJB), blk, 0, stream>>>(
      COSTD, NFSQ, NMUSQ, GBUF, LSC, LSE, out, FLG, logp, logq);

  // predictor MLP (mlp_bnstats fused: producer atomics + consumer recompute)
  mlp_gemm<false, true><<<dim3(BB * HH / 4), blk, 0, stream>>>(
      mw1, mb1, GMAX, MH1, nullptr, nullptr, nullptr, nullptr, MSS1, MSQ1, HH, DD);
  mlp_gemm<true, true><<<dim3(BB * HH / 4), blk, 0, stream>>>(
      mw2, mb2, MH1, MH2, MSS1, MSQ1, mg1, mt1, MSS2, MSQ2, HH, HH);
  mlp_gemm<true, false><<<dim3(BB * PP / 4), blk, 0, stream>>>(
      mw3, mb3, MH2, out + 1 + BB * PP * KC, MSS2, MSQ2, mg2, mt2, nullptr, nullptr, PP, HH);

  // projector conv head (bnstats fused; pi-divide inline on raw vlad)
  gemm_conv<64, 32, 16, 4, 2, false, true, true><<<dim3(1, HH / 64, BB), blk, 0, stream>>>(
      pw1, pb1, VLAD, T1, PIRAW, nullptr, nullptr, nullptr, nullptr, 0.f, PS1, PQ1, HH, DD, KC);
  gemm_conv<64, 32, 16, 4, 2, true, true, false><<<dim3(1, HH / 64, BB), blk, 0, stream>>>(
      pw2, pb2, T1, T2, nullptr, PS1, PQ1, pg1, pt1, CNT_PJ, PS2, PQ2, HH, HH, KC);
  gemm_conv<64, 32, 16, 4, 2, true, false, false><<<dim3(1, PP / 64, BB), blk, 0, stream>>>(
      pw3, pb3, T2, out + 1, nullptr, PS2, PQ2, pg2, pt2, CNT_PJ, nullptr, nullptr, PP, HH, KC);
}

// Round 10
// 1005.489 us; speedup vs baseline: 1.2193x; 1.1424x over previous
//
#include <hip/hip_runtime.h>
#include <cmath>

#define BB 8
#define DD 1024
#define NP 4096
#define KC 32
#define HH 512
#define PP 128
#define NJB 16          // sinkhorn blocks per batch
#define BN_EPS 1e-5f
#define NSLOT 32        // BN stat accumulation slots (8 bz x 4 n-quadrant)
// flag offsets inside FLG (uints): sinkhorn uses [0,3200)
#define FOFF_M1 3200
#define FOFF_M2 3216
#define FOFF_P1 3232
#define FOFF_P2 3296

typedef unsigned short u16;
typedef unsigned long long u64;
typedef short s16x8 __attribute__((ext_vector_type(8)));
typedef float f32x4 __attribute__((ext_vector_type(4)));

// ---------------- wave helpers ----------------
__device__ __forceinline__ float waveReduceSum(float v) {
#pragma unroll
  for (int o = 32; o > 0; o >>= 1) v += __shfl_down(v, o, 64);
  return v;
}

// ---------------- bf16 3-way split: y = h + m + l + O(2^-24 |y|) ----------
__device__ __forceinline__ void split3(float y, short& h, short& m, short& l) {
  unsigned uy = __float_as_uint(y);
  h = (short)(uy >> 16);
  float r1 = y - __uint_as_float(uy & 0xFFFF0000u);
  unsigned um = __float_as_uint(r1);
  m = (short)(um >> 16);
  float r2 = r1 - __uint_as_float(um & 0xFFFF0000u);
  l = (short)(__float_as_uint(r2) >> 16);
}

// ---------------- shadow-group barrier: plain stores made visible via
// release fence -> scoped flag; consumers poll then acquire fence.
// Used a handful of times per chain (hidden under sinkhorn) - NOT per-iter.
__device__ void shadowBar(unsigned* flg, int nb, int myid) {
  __threadfence();              // release: drain + write back this thread's stores
  __syncthreads();              // all threads of block fenced
  if (threadIdx.x == 0)
    __hip_atomic_store(&flg[myid], 1u, __ATOMIC_RELAXED, __HIP_MEMORY_SCOPE_AGENT);
  if ((int)threadIdx.x < nb)
    while (__hip_atomic_load(&flg[threadIdx.x], __ATOMIC_RELAXED, __HIP_MEMORY_SCOPE_AGENT) == 0u)
      __builtin_amdgcn_s_sleep(2);
  __syncthreads();
  __threadfence();              // acquire: invalidate stale cached lines
}

// ---------------- W pre-permute + 3-split (+ zero BN accumulators with idle blocks)
__global__ __launch_bounds__(256) void convW3_all(
    const float* __restrict__ W1, u16* __restrict__ h1, u16* __restrict__ m1, u16* __restrict__ l1,
    const float* __restrict__ W2, u16* __restrict__ h2, u16* __restrict__ m2, u16* __restrict__ l2,
    const float* __restrict__ W3, u16* __restrict__ h3, u16* __restrict__ m3, u16* __restrict__ l3,
    float* __restrict__ zbuf) {
  int z = blockIdx.z;
  if (z == 2 && blockIdx.x >= 1) {
    int id = (blockIdx.x - 1) * 32 + blockIdx.y;   // 0..95
#pragma unroll
    for (int k2 = 0; k2 < 3; k2++) {
      int idx = k2 * 24576 + id * 256 + (int)threadIdx.x;
      if (idx < 69632) zbuf[idx] = 0.f;
    }
    return;
  }
  const float* W; u16 *hb, *mb, *lb; int K, BM, MTt, KCH;
  if (z == 0)      { W = W1; hb = h1; mb = m1; lb = l1; K = 1024; BM = 128; MTt = 4; KCH = 32; }
  else if (z == 1) { W = W2; hb = h2; mb = m2; lb = l2; K = 512;  BM = 128; MTt = 4; KCH = 16; }
  else             { W = W3; hb = h3; mb = m3; lb = l3; K = 512;  BM = 32;  MTt = 1; KCH = 16; }
  int mt = blockIdx.x, kc = blockIdx.y;
  if (mt >= MTt || kc >= KCH) return;
  const int AU = BM * 4;
  for (int u = threadIdx.x; u < AU; u += 256) {
    int q = u / BM, m = u % BM;
    const float* wp = W + (size_t)(mt * BM + m) * K + kc * 32 + q * 8;
    s16x8 hv, mv, lv;
#pragma unroll
    for (int j = 0; j < 8; j++) {
      short h, mm, l; split3(wp[j], h, mm, l);
      hv[j] = h; mv[j] = mm; lv[j] = l;
    }
    size_t ob = ((size_t)(mt * KCH + kc)) * (size_t)(BM * 32) + (size_t)u * 8;
    *(s16x8*)(hb + ob) = hv;
    *(s16x8*)(mb + ob) = mv;
    *(s16x8*)(lb + ob) = lv;
  }
}

// ---------------- bf16x3 MFMA GEMM, reg-prefetch pipelined (unchanged from R9)
template<int BM, int MBLK, int MT, int NT, int WM, bool BNRELU, bool ACCST, bool SMAX>
__global__ __launch_bounds__(256) void gemm_mfma3(
    const u16* __restrict__ wh, const u16* __restrict__ wmid, const u16* __restrict__ wl,
    const float* __restrict__ bias, const float* __restrict__ X,
    const float* __restrict__ insum, const float* __restrict__ insq,
    const float* __restrict__ bng, const float* __restrict__ bnb, float cnt,
    float* __restrict__ Y, int K, int M,
    float* __restrict__ gsum, float* __restrict__ gsq,
    float* __restrict__ score, float* __restrict__ lse, float* __restrict__ piraw) {
  __shared__ s16x8 AhS[BM * 4], AmS[BM * 4], AlS[BM * 4];
  __shared__ s16x8 BhS[512], BmS[512], BlS[512];
  __shared__ float scS[512], shS[512];
  const int KCH = K / 32;
  const int tid = threadIdx.x;
  const int bz = blockIdx.z;
  int bid = blockIdx.x;
  int xs = bid & 7, rr = bid >> 3;
  int m_idx = rr % MBLK;
  int n_idx = xs + 8 * (rr / MBLK);

  const int w = tid >> 6, l = tid & 63, q = l >> 4, col = l & 15;
  const int wm = (WM == 1) ? 0 : (w >> 1);
  const int wn = (WM == 1) ? w : (w & 1);
  constexpr int NA = (BM * 4 + 255) / 256;

  if (BNRELU) {
    for (int c0 = tid; c0 < K; c0 += 256) {
      float s = 0.f, q2 = 0.f;
      for (int sl = 0; sl < NSLOT; sl++) { s += insum[sl * 512 + c0]; q2 += insq[sl * 512 + c0]; }
      float mean = s / cnt;
      float var = q2 / cnt - mean * mean;
      float sc = bng[c0] / sqrtf(var + BN_EPS);
      scS[c0] = sc; shS[c0] = bnb[c0] - mean * sc;
    }
    __syncthreads();
  }

  f32x4 acc[MT][NT];
#pragma unroll
  for (int i = 0; i < MT; i++)
#pragma unroll
    for (int j = 0; j < NT; j++) { acc[i][j][0] = 0.f; acc[i][j][1] = 0.f; acc[i][j][2] = 0.f; acc[i][j][3] = 0.f; }

  const short* Ah = (const short*)AhS;
  const short* Am = (const short*)AmS;
  const short* Al = (const short*)AlS;
  const short* Bh = (const short*)BhS;
  const short* Bm = (const short*)BmS;
  const short* Bl = (const short*)BlS;

  const float* Xb = X + (size_t)bz * (size_t)K * NP + (size_t)n_idx * 128;
  const size_t abase = (size_t)m_idx * KCH * (size_t)(BM * 32);

  s16x8 rAh[NA], rAm[NA], rAl[NA];
  float rB[2][8];

  {
    const s16x8* awh = (const s16x8*)(wh + abase);
    const s16x8* awm = (const s16x8*)(wmid + abase);
    const s16x8* awl = (const s16x8*)(wl + abase);
#pragma unroll
    for (int t = 0; t < NA; t++) {
      int u = tid + t * 256;
      if (u < BM * 4) { rAh[t] = awh[u]; rAm[t] = awm[u]; rAl[t] = awl[u]; }
    }
#pragma unroll
    for (int t = 0; t < 2; t++) {
      int u = tid + t * 256;
      int qq = u >> 7, n = u & 127;
      const float* fp = Xb + (size_t)(qq * 8) * NP + n;
#pragma unroll
      for (int j = 0; j < 8; j++) {
        float y = fp[(size_t)j * NP];
        if (BNRELU) y = fmaxf(fmaf(y, scS[qq * 8 + j], shS[qq * 8 + j]), 0.f);
        rB[t][j] = y;
      }
    }
  }

  for (int kc = 0; kc < KCH; kc++) {
#pragma unroll
    for (int t = 0; t < NA; t++) {
      int u = tid + t * 256;
      if (u < BM * 4) { AhS[u] = rAh[t]; AmS[u] = rAm[t]; AlS[u] = rAl[t]; }
    }
#pragma unroll
    for (int t = 0; t < 2; t++) {
      int u = tid + t * 256;
      s16x8 hv, mv, lv;
#pragma unroll
      for (int j = 0; j < 8; j++) {
        short h, mm, ll; split3(rB[t][j], h, mm, ll);
        hv[j] = h; mv[j] = mm; lv[j] = ll;
      }
      BhS[u] = hv; BmS[u] = mv; BlS[u] = lv;
    }
    __syncthreads();

    if (kc + 1 < KCH) {
      size_t ab = abase + (size_t)(kc + 1) * (size_t)(BM * 32);
      const s16x8* awh = (const s16x8*)(wh + ab);
      const s16x8* awm = (const s16x8*)(wmid + ab);
      const s16x8* awl = (const s16x8*)(wl + ab);
#pragma unroll
      for (int t = 0; t < NA; t++) {
        int u = tid + t * 256;
        if (u < BM * 4) { rAh[t] = awh[u]; rAm[t] = awm[u]; rAl[t] = awl[u]; }
      }
      const int kp = (kc + 1) * 32;
#pragma unroll
      for (int t = 0; t < 2; t++) {
        int u = tid + t * 256;
        int qq = u >> 7, n = u & 127;
        const float* fp = Xb + (size_t)(kp + qq * 8) * NP + n;
#pragma unroll
        for (int j = 0; j < 8; j++) {
          float y = fp[(size_t)j * NP];
          if (BNRELU) y = fmaxf(fmaf(y, scS[kp + qq * 8 + j], shS[kp + qq * 8 + j]), 0.f);
          rB[t][j] = y;
        }
      }
    }

    s16x8 ah[MT], am[MT], al[MT];
#pragma unroll
    for (int i = 0; i < MT; i++) {
      int off = (q * BM + wm * (MT * 16) + i * 16 + col) * 8;
      ah[i] = *(const s16x8*)(Ah + off);
      am[i] = *(const s16x8*)(Am + off);
      al[i] = *(const s16x8*)(Al + off);
    }
    __builtin_amdgcn_s_setprio(1);
#pragma unroll
    for (int j = 0; j < NT; j++) {
      int offb = (q * 128 + wn * (NT * 16) + j * 16 + col) * 8;
      s16x8 bh = *(const s16x8*)(Bh + offb);
      s16x8 bm = *(const s16x8*)(Bm + offb);
      s16x8 bl = *(const s16x8*)(Bl + offb);
#pragma unroll
      for (int i = 0; i < MT; i++) {
        acc[i][j] = __builtin_amdgcn_mfma_f32_16x16x32_bf16(ah[i], bh, acc[i][j], 0, 0, 0);
        acc[i][j] = __builtin_amdgcn_mfma_f32_16x16x32_bf16(ah[i], bm, acc[i][j], 0, 0, 0);
        acc[i][j] = __builtin_amdgcn_mfma_f32_16x16x32_bf16(am[i], bh, acc[i][j], 0, 0, 0);
        acc[i][j] = __builtin_amdgcn_mfma_f32_16x16x32_bf16(ah[i], bl, acc[i][j], 0, 0, 0);
        acc[i][j] = __builtin_amdgcn_mfma_f32_16x16x32_bf16(am[i], bm, acc[i][j], 0, 0, 0);
        acc[i][j] = __builtin_amdgcn_mfma_f32_16x16x32_bf16(al[i], bh, acc[i][j], 0, 0, 0);
      }
    }
    __builtin_amdgcn_s_setprio(0);
    __syncthreads();
  }

  if (!SMAX) {
    float* red = (float*)AhS;
#pragma unroll
    for (int i = 0; i < MT; i++) {
#pragma unroll
      for (int r = 0; r < 4; r++) {
        int ml = wm * (MT * 16) + i * 16 + q * 4 + r;
        int m = m_idx * BM + ml;
        float bv = bias[m];
        float ys = 0.f, yq = 0.f;
#pragma unroll
        for (int j = 0; j < NT; j++) {
          int n = n_idx * 128 + wn * (NT * 16) + j * 16 + col;
          float y = acc[i][j][r] + bv;
          Y[((size_t)bz * M + m) * 4096 + n] = y;
          ys += y; yq = fmaf(y, y, yq);
        }
        if (ACCST) {
#pragma unroll
          for (int o = 1; o < 16; o <<= 1) { ys += __shfl_xor(ys, o, 64); yq += __shfl_xor(yq, o, 64); }
          if (col == 0) { red[ml * 4 + wn * 2] = ys; red[ml * 4 + wn * 2 + 1] = yq; }
        }
      }
    }
    if (ACCST) {
      __syncthreads();
      if (tid < BM) {
        int slot = bz * 4 + (rr / MBLK);
        atomicAdd(&gsum[slot * 512 + m_idx * BM + tid], red[tid * 4] + red[tid * 4 + 2]);
        atomicAdd(&gsq [slot * 512 + m_idx * BM + tid], red[tid * 4 + 1] + red[tid * 4 + 3]);
      }
    }
  } else {
    float yv[MT][NT][4];
#pragma unroll
    for (int i = 0; i < MT; i++) {
#pragma unroll
      for (int r = 0; r < 4; r++) {
        int m = i * 16 + q * 4 + r;
        float bv = bias[m];
#pragma unroll
        for (int j = 0; j < NT; j++) {
          int n = n_idx * 128 + wn * (NT * 16) + j * 16 + col;
          float y = acc[i][j][r] + bv;
          Y[((size_t)bz * M + m) * 4096 + n] = y;
          yv[i][j][r] = y;
        }
      }
    }
    float* redP = (float*)AhS;
    if (tid < KC) redP[tid] = 0.f;
    __syncthreads();
    float pl[MT][4];
#pragma unroll
    for (int i = 0; i < MT; i++)
#pragma unroll
      for (int r = 0; r < 4; r++) pl[i][r] = 0.f;
#pragma unroll
    for (int j = 0; j < NT; j++) {
      float mx = -1e30f;
#pragma unroll
      for (int i = 0; i < MT; i++)
#pragma unroll
        for (int r = 0; r < 4; r++) mx = fmaxf(mx, yv[i][j][r]);
      mx = fmaxf(mx, __shfl_xor(mx, 16, 64));
      mx = fmaxf(mx, __shfl_xor(mx, 32, 64));
      float e[MT][4]; float s = 0.f;
#pragma unroll
      for (int i = 0; i < MT; i++)
#pragma unroll
        for (int r = 0; r < 4; r++) { e[i][r] = expf(yv[i][j][r] - mx); s += e[i][r]; }
      s += __shfl_xor(s, 16, 64);
      s += __shfl_xor(s, 32, 64);
      float inv = 1.f / s;
      int n = n_idx * 128 + wn * (NT * 16) + j * 16 + col;
#pragma unroll
      for (int i = 0; i < MT; i++)
#pragma unroll
        for (int r = 0; r < 4; r++) {
          float sv = e[i][r] * inv;
          int m = i * 16 + q * 4 + r;
          score[((size_t)bz * KC + m) * NP + n] = sv;
          pl[i][r] += sv;
        }
      if ((tid & 48) == 0) lse[(size_t)bz * NP + n] = mx + logf(s);
    }
#pragma unroll
    for (int i = 0; i < MT; i++)
#pragma unroll
      for (int r = 0; r < 4; r++) atomicAdd(&redP[i * 16 + q * 4 + r], pl[i][r]);
    __syncthreads();
    if (tid < KC) atomicAdd(&piraw[bz * KC + tid], redP[tid]);
  }
}

// ---------------- vlad accumulation (split over n, atomic) — RAW (undivided) vlad
__global__ __launch_bounds__(256) void vlad_accum(
    const float* __restrict__ feat, const float* __restrict__ score, float* __restrict__ vlad) {
  const int SPLIT_LEN = NP / 8;
  int sp = blockIdx.x, dt = blockIdx.y, b = blockIdx.z;
  int d0 = dt * 128;
  int n_start = sp * SPLIT_LEN;
  __shared__ float As[32][132];
  __shared__ float Bs[32][36];
  int tid = threadIdx.x;
  int tx = tid % 16;
  int ty = tid / 16;
  float acc[8][2] = {};
  const float* fb = feat + (size_t)b * DD * NP;
  const float* sb = score + (size_t)b * KC * NP;
  for (int nc = 0; nc < SPLIT_LEN; nc += 32) {
    int n0 = n_start + nc;
    for (int i = tid; i < 128 * 32; i += 256) {
      int r = i >> 5, c = i & 31;
      As[c][r] = fb[(size_t)(d0 + r) * NP + n0 + c];
    }
    for (int i = tid; i < 32 * 32; i += 256) {
      int r = i >> 5, c = i & 31;
      Bs[c][r] = sb[(size_t)r * NP + n0 + c];
    }
    __syncthreads();
#pragma unroll 4
    for (int kk = 0; kk < 32; kk++) {
      float ra[8], rb[2];
#pragma unroll
      for (int i = 0; i < 8; i++) ra[i] = As[kk][ty * 8 + i];
      rb[0] = Bs[kk][tx * 2]; rb[1] = Bs[kk][tx * 2 + 1];
#pragma unroll
      for (int i = 0; i < 8; i++) { acc[i][0] = fmaf(ra[i], rb[0], acc[i][0]); acc[i][1] = fmaf(ra[i], rb[1], acc[i][1]); }
    }
    __syncthreads();
  }
#pragma unroll
  for (int i = 0; i < 8; i++)
#pragma unroll
    for (int j = 0; j < 2; j++)
      atomicAdd(&vlad[((size_t)b * DD + d0 + ty * 8 + i) * KC + tx * 2 + j], acc[i][j]);
}

// ---------------- cost dot accumulation + fused pi-divide/||f||^2/||mu||^2/gmax
__global__ __launch_bounds__(256) void cost_accum(
    const float* __restrict__ feat, const float* __restrict__ vlad,
    const float* __restrict__ piraw, float* __restrict__ costd,
    float* __restrict__ nfsq, float* __restrict__ nmusq, float* __restrict__ gmax) {
  int sp = blockIdx.x, nt = blockIdx.y, b = blockIdx.z;
  int n0 = nt * 128;
  int d_start = sp * (DD / 4);
  __shared__ float As[32][132];
  __shared__ float Bs[32][36];
  __shared__ float nfs[128];
  __shared__ float piS[KC];
  __shared__ float nms[KC];
  int tid = threadIdx.x;
  int tx = tid % 16;
  int ty = tid / 16;
  if (tid < KC) { piS[tid] = fmaxf(piraw[b * KC + tid], 1e-4f); nms[tid] = 0.f; }
  __syncthreads();
  float acc[8][2] = {};
  float sq = 0.f, nm_local = 0.f;
  const float* fb = feat + (size_t)b * DD * NP;
  const float* vb = vlad + (size_t)b * DD * KC;
  for (int dc = 0; dc < DD / 4; dc += 32) {
    int dd0 = d_start + dc;
    for (int i = tid; i < 32 * 128; i += 256) {
      int r = i >> 7, c = i & 127;
      float v = fb[(size_t)(dd0 + r) * NP + n0 + c];
      As[r][c] = v;
      sq = fmaf(v, v, sq);
    }
    for (int i = tid; i < 32 * 32; i += 256) {
      int r = i >> 5, c = i & 31;
      float v = vb[(size_t)(dd0 + r) * KC + c] / piS[c];
      Bs[r][c] = v;
      if (nt == 0) nm_local = fmaf(v, v, nm_local);
    }
    __syncthreads();
    if (nt == 0 && tid < 32) {
      float gm = -1e30f;
#pragma unroll
      for (int c = 0; c < KC; c++) gm = fmaxf(gm, Bs[tid][c]);
      gmax[(size_t)b * DD + dd0 + tid] = gm;
    }
#pragma unroll 4
    for (int kk = 0; kk < 32; kk++) {
      float ra[8], rb[2];
#pragma unroll
      for (int i = 0; i < 8; i++) ra[i] = As[kk][ty * 8 + i];
      rb[0] = Bs[kk][tx * 2]; rb[1] = Bs[kk][tx * 2 + 1];
#pragma unroll
      for (int i = 0; i < 8; i++) { acc[i][0] = fmaf(ra[i], rb[0], acc[i][0]); acc[i][1] = fmaf(ra[i], rb[1], acc[i][1]); }
    }
    __syncthreads();
  }
#pragma unroll
  for (int i = 0; i < 8; i++)
#pragma unroll
    for (int j = 0; j < 2; j++)
      atomicAdd(&costd[((size_t)b * NP + n0 + ty * 8 + i) * KC + tx * 2 + j], acc[i][j]);
  if (tid < 128) nfs[tid] = 0.f;
  __syncthreads();
  atomicAdd(&nfs[tid & 127], sq);
  if (nt == 0) atomicAdd(&nms[tid & 31], nm_local);
  __syncthreads();
  if (tid < 128) atomicAdd(&nfsq[(size_t)b * NP + n0 + tid], nfs[tid]);
  if (nt == 0 && tid < KC) atomicAdd(&nmusq[b * KC + tid], nms[tid]);
}

// ---------------- projector conv layer as device function (runs in tail_all shadow
// blocks). BM=64,BN=32,BK=16,TM=4,TN=2. Plain stores; visibility via shadowBar.
template<bool BNRELU, bool ACCST, bool PDIV>
__device__ void proj_layer(float (*As)[68], float (*Xs)[36], float* scS, float* shS, float* piS,
    const float* __restrict__ W, const float* __restrict__ bias,
    const float* __restrict__ X, float* __restrict__ Y,
    const float* __restrict__ pidiv,
    const float* __restrict__ insum, const float* __restrict__ insq,
    const float* __restrict__ bng, const float* __restrict__ bnb, float cnt,
    float* __restrict__ gsum, float* __restrict__ gsq,
    int M, int K, int b, int m0) {
  const int tid = threadIdx.x;
  const int tx = tid % 16;
  const int ty = tid / 16;
  if (PDIV && tid < KC) piS[tid] = fmaxf(pidiv[b * KC + tid], 1e-4f);
  if (BNRELU) {
    for (int c0 = tid; c0 < K; c0 += 256) {
      float mean = insum[c0] / cnt;
      float var = insq[c0] / cnt - mean * mean;
      float sc = bng[c0] / sqrtf(var + BN_EPS);
      scS[c0] = sc; shS[c0] = bnb[c0] - mean * sc;
    }
  }
  __syncthreads();
  const float* Xb = X + (size_t)b * K * KC;
  float acc[4][2] = {};
  for (int k0 = 0; k0 < K; k0 += 16) {
    for (int i = tid; i < 64 * 16; i += 256) {
      int r = i / 16, c = i % 16;
      As[c][r] = W[(size_t)(m0 + r) * K + k0 + c];
    }
    for (int i = tid; i < 16 * 32; i += 256) {
      int r = i / 32, c = i % 32;
      float x = Xb[(size_t)(k0 + r) * KC + c];
      if (PDIV) x /= piS[c];
      if (BNRELU) x = fmaxf(fmaf(x, scS[k0 + r], shS[k0 + r]), 0.f);
      Xs[r][c] = x;
    }
    __syncthreads();
#pragma unroll 4
    for (int kk = 0; kk < 16; kk++) {
      float ra[4], rb[2];
#pragma unroll
      for (int i = 0; i < 4; i++) ra[i] = As[kk][ty * 4 + i];
      rb[0] = Xs[kk][tx * 2]; rb[1] = Xs[kk][tx * 2 + 1];
#pragma unroll
      for (int i = 0; i < 4; i++) { acc[i][0] = fmaf(ra[i], rb[0], acc[i][0]); acc[i][1] = fmaf(ra[i], rb[1], acc[i][1]); }
    }
    __syncthreads();
  }
  float* red = (float*)As;
  if (ACCST) {
    if (tid < 128) red[tid] = 0.f;
    __syncthreads();
  }
#pragma unroll
  for (int i = 0; i < 4; i++) {
    int ml = ty * 4 + i;
    float bm = bias[m0 + ml];
    float ys = 0.f, yq = 0.f;
#pragma unroll
    for (int j = 0; j < 2; j++) {
      float y = acc[i][j] + bm;
      Y[((size_t)b * M + m0 + ml) * KC + tx * 2 + j] = y;
      ys += y; yq = fmaf(y, y, yq);
    }
    if (ACCST) {
      atomicAdd(&red[ml * 2], ys);
      atomicAdd(&red[ml * 2 + 1], yq);
    }
  }
  if (ACCST) {
    __syncthreads();
    if (tid < 64) {
      atomicAdd(&gsum[m0 + tid], red[tid * 2]);
      atomicAdd(&gsq [m0 + tid], red[tid * 2 + 1]);
    }
  }
}

// ---------------- tail_all: sinkhorn (blocks 0..127) + MLP chain (128..143)
// + projector chain (144..207) executing in sinkhorn's shadow.
__global__ __launch_bounds__(256) void tail_all(
    const float* __restrict__ costd, const float* __restrict__ nfsq,
    const float* __restrict__ nmusq, u64* __restrict__ G,
    const float* __restrict__ LSm, const float* __restrict__ lseArr,
    float* __restrict__ out0, unsigned* __restrict__ flags,
    float logp, float logq,
    const float* __restrict__ mw1, const float* __restrict__ mb1,
    const float* __restrict__ mg1, const float* __restrict__ mt1,
    const float* __restrict__ mw2, const float* __restrict__ mb2,
    const float* __restrict__ mg2, const float* __restrict__ mt2,
    const float* __restrict__ mw3, const float* __restrict__ mb3,
    const float* __restrict__ gmax, float* __restrict__ mh1, float* __restrict__ mh2,
    float* __restrict__ outm,
    float* __restrict__ mss1, float* __restrict__ msq1,
    float* __restrict__ mss2, float* __restrict__ msq2,
    const float* __restrict__ pw1, const float* __restrict__ pb1,
    const float* __restrict__ pg1, const float* __restrict__ pt1,
    const float* __restrict__ pw2, const float* __restrict__ pb2,
    const float* __restrict__ pg2, const float* __restrict__ pt2,
    const float* __restrict__ pw3, const float* __restrict__ pb3,
    const float* __restrict__ vlad, const float* __restrict__ piraw,
    float* __restrict__ t1, float* __restrict__ t2, float* __restrict__ outp,
    float* __restrict__ ps1, float* __restrict__ pq1,
    float* __restrict__ ps2, float* __restrict__ pq2) {
  __shared__ float smemF[9216];   // 36 KB arena shared by the three roles
  const int bid = blockIdx.x;
  const int tid = threadIdx.x;

  if (bid < 128) {
    // ================= SINKHORN (identical logic to R9, LDS re-carved) ======
    const float EPS = 1e-3f, IEPS = 1000.f;
    float* vsh  = smemF;            // 32
    float* nmS  = smemF + 32;       // 32
    float* bmS  = smemF + 64;       // 32
    float* redL = smemF + 96;       // 4
    float* v25S = smemF + 100;      // 32
    float (*vals)[33] = (float(*)[33])(smemF + 160);            // 8448
    float (*red)[9]   = (float(*)[9])(smemF + 160 + 8448);      // 288
    int b = bid / NJB, j = bid % NJB;
    int n = j * 256 + tid;

    if (tid < KC) nmS[tid] = fmaxf(sqrtf(nmusq[b * KC + tid]), 1e-12f);
    __syncthreads();

    float c[KC];
    {
      const float* dp = costd + ((size_t)b * NP + n) * KC;
      float nf = fmaxf(sqrtf(nfsq[(size_t)b * NP + n]), 1e-12f);
#pragma unroll
      for (int k = 0; k < KC; k++) c[k] = 2.f - 2.f * dp[k] / (nf * nmS[k]);
    }

    const int kk = tid & 31, seg = tid >> 5;
    const int r0 = seg * 32;
    float u = 0.f;

    for (int t = 1; t <= 25; t++) {
      if (t > 1) {
        if (tid < NJB) {
          const unsigned* fp = flags + ((size_t)(t - 2) * BB + b) * NJB;
          while (__hip_atomic_load(&fp[tid], __ATOMIC_RELAXED, __HIP_MEMORY_SCOPE_AGENT) == 0u)
            __builtin_amdgcn_s_sleep(1);
        }
        __syncthreads();
      }
      if (tid < KC) {
        float v = 0.f;
        if (t > 1) {
          const u64* Gp = G + (((size_t)(t - 2) * BB + b) * NJB) * KC;
          float gm[NJB], gs[NJB];
#pragma unroll
          for (int jj = 0; jj < NJB; jj++) {
            u64 raw = __hip_atomic_load(&Gp[jj * KC + tid], __ATOMIC_RELAXED, __HIP_MEMORY_SCOPE_AGENT);
            gm[jj] = __uint_as_float((unsigned)raw);
            gs[jj] = __uint_as_float((unsigned)(raw >> 32));
          }
          float m = -1e30f;
#pragma unroll
          for (int jj = 0; jj < NJB; jj++) m = fmaxf(m, gm[jj]);
          float s = 0.f;
#pragma unroll
          for (int jj = 0; jj < NJB; jj++) s += gs[jj] * expf(gm[jj] - m);
          v = EPS * logq - EPS * (m + logf(s));
        }
        vsh[tid] = v;
      }
      __syncthreads();
      float m = -1e30f;
#pragma unroll
      for (int k = 0; k < KC; k++) m = fmaxf(m, vsh[k] - c[k]);
      float s = 0.f;
#pragma unroll
      for (int k = 0; k < KC; k++) s += expf((vsh[k] - c[k] - m) * IEPS);
      u = EPS * logp - m - EPS * logf(s);
#pragma unroll
      for (int k = 0; k < KC; k++) vals[tid][k] = (u - c[k]) * IEPS;
      __syncthreads();
      {
        float lm = -1e30f;
        for (int r = 0; r < 32; r++) lm = fmaxf(lm, vals[r0 + r][kk]);
        red[kk][seg] = lm;
      }
      __syncthreads();
      if (tid < KC) {
        float bm = red[tid][0];
        for (int i2 = 1; i2 < 8; i2++) bm = fmaxf(bm, red[tid][i2]);
        bmS[tid] = bm;
      }
      __syncthreads();
      {
        float bm = bmS[kk];
        float ls = 0.f;
        for (int r = 0; r < 32; r++) ls += expf(vals[r0 + r][kk] - bm);
        red[kk][seg] = ls;
      }
      __syncthreads();
      if (tid < KC) {
        float s8 = 0.f;
        for (int i2 = 0; i2 < 8; i2++) s8 += red[tid][i2];
        u64 raw = (u64)__float_as_uint(bmS[tid]) | ((u64)__float_as_uint(s8) << 32);
        u64* Gp = G + (((size_t)(t - 1) * BB + b) * NJB + j) * KC + tid;
        __hip_atomic_store(Gp, raw, __ATOMIC_RELAXED, __HIP_MEMORY_SCOPE_AGENT);
      }
      __syncthreads();
      if (tid == 0) {
        unsigned* fl = flags + ((size_t)(t - 1) * BB + b) * NJB + j;
        __hip_atomic_store(fl, 1u, __ATOMIC_RELAXED, __HIP_MEMORY_SCOPE_AGENT);
      }
    }

    if (tid < NJB) {
      const unsigned* fp = flags + ((size_t)24 * BB + b) * NJB;
      while (__hip_atomic_load(&fp[tid], __ATOMIC_RELAXED, __HIP_MEMORY_SCOPE_AGENT) == 0u)
        __builtin_amdgcn_s_sleep(1);
    }
    __syncthreads();
    if (tid < KC) {
      const u64* Gp = G + (((size_t)24 * BB + b) * NJB) * KC;
      float gm[NJB], gs[NJB];
#pragma unroll
      for (int jj = 0; jj < NJB; jj++) {
        u64 raw = __hip_atomic_load(&Gp[jj * KC + tid], __ATOMIC_RELAXED, __HIP_MEMORY_SCOPE_AGENT);
        gm[jj] = __uint_as_float((unsigned)raw);
        gs[jj] = __uint_as_float((unsigned)(raw >> 32));
      }
      float m = -1e30f;
#pragma unroll
      for (int jj = 0; jj < NJB; jj++) m = fmaxf(m, gm[jj]);
      float s = 0.f;
#pragma unroll
      for (int jj = 0; jj < NJB; jj++) s += gs[jj] * expf(gm[jj] - m);
      v25S[tid] = EPS * logq - EPS * (m + logf(s));
    }
    __syncthreads();
    float lsev = lseArr[(size_t)b * NP + n];
    float part = 0.f;
#pragma unroll
    for (int k = 0; k < KC; k++) {
      float gamma = expf((u + v25S[k] - c[k]) * IEPS);
      float logsm = LSm[((size_t)b * KC + k) * NP + n] - lsev;
      part += gamma * logsm;
    }
    part *= (float)NP;
    int lane = tid & 63, wid = tid >> 6;
    part = waveReduceSum(part);
    if (lane == 0) redL[wid] = part;
    __syncthreads();
    if (tid == 0) {
      float tt = redL[0] + redL[1] + redL[2] + redL[3];
      atomicAdd(out0, -tt / (float)(BB * NP));
    }
  } else if (bid < 144) {
    // ================= MLP chain (16 blocks = 64 waves) =====================
    float* scS = smemF;          // 512
    float* shS = smemF + 512;    // 512
    int mid = bid - 128;
    int wv = mid * 4 + (tid >> 6);
    int lane = tid & 63;
    // layer 1: 4096 outputs, K=1024, no BN
    for (int t = 0; t < 64; t++) {
      int idx = wv * 64 + t;
      int s = idx >> 9, jj = idx & 511;
      const float4* ip = (const float4*)(gmax + (size_t)s * DD);
      const float4* wp = (const float4*)(mw1 + (size_t)jj * DD);
      float acc = 0.f;
      for (int c4 = lane; c4 < DD / 4; c4 += 64) {
        float4 x = ip[c4]; float4 w = wp[c4];
        acc += x.x * w.x + x.y * w.y + x.z * w.z + x.w * w.w;
      }
      acc = waveReduceSum(acc);
      if (lane == 0) {
        float y = acc + mb1[jj];
        mh1[idx] = y;
        atomicAdd(&mss1[jj], y); atomicAdd(&msq1[jj], y * y);
      }
    }
    shadowBar(flags + FOFF_M1, 16, mid);
    for (int c0 = tid; c0 < HH; c0 += 256) {
      float mean = mss1[c0] * 0.125f;
      float var = msq1[c0] * 0.125f - mean * mean;
      float sc = mg1[c0] / sqrtf(var + BN_EPS);
      scS[c0] = sc; shS[c0] = mt1[c0] - mean * sc;
    }
    __syncthreads();
    // layer 2: 4096 outputs, K=512, BN+ReLU
    for (int t = 0; t < 64; t++) {
      int idx = wv * 64 + t;
      int s = idx >> 9, jj = idx & 511;
      const float4* ip = (const float4*)(mh1 + (size_t)s * HH);
      const float4* wp = (const float4*)(mw2 + (size_t)jj * HH);
      float acc = 0.f;
      for (int c4 = lane; c4 < HH / 4; c4 += 64) {
        float4 x = ip[c4]; float4 w = wp[c4];
        int cb = c4 * 4;
        x.x = fmaxf(fmaf(x.x, scS[cb + 0], shS[cb + 0]), 0.f);
        x.y = fmaxf(fmaf(x.y, scS[cb + 1], shS[cb + 1]), 0.f);
        x.z = fmaxf(fmaf(x.z, scS[cb + 2], shS[cb + 2]), 0.f);
        x.w = fmaxf(fmaf(x.w, scS[cb + 3], shS[cb + 3]), 0.f);
        acc += x.x * w.x + x.y * w.y + x.z * w.z + x.w * w.w;
      }
      acc = waveReduceSum(acc);
      if (lane == 0) {
        float y = acc + mb2[jj];
        mh2[idx] = y;
        atomicAdd(&mss2[jj], y); atomicAdd(&msq2[jj], y * y);
      }
    }
    shadowBar(flags + FOFF_M2, 16, mid);
    for (int c0 = tid; c0 < HH; c0 += 256) {
      float mean = mss2[c0] * 0.125f;
      float var = msq2[c0] * 0.125f - mean * mean;
      float sc = mg2[c0] / sqrtf(var + BN_EPS);
      scS[c0] = sc; shS[c0] = mt2[c0] - mean * sc;
    }
    __syncthreads();
    // layer 3: 1024 outputs, K=512, BN+ReLU
    for (int t = 0; t < 16; t++) {
      int idx = wv * 16 + t;
      int s = idx >> 7, jj = idx & 127;
      const float4* ip = (const float4*)(mh2 + (size_t)s * HH);
      const float4* wp = (const float4*)(mw3 + (size_t)jj * HH);
      float acc = 0.f;
      for (int c4 = lane; c4 < HH / 4; c4 += 64) {
        float4 x = ip[c4]; float4 w = wp[c4];
        int cb = c4 * 4;
        x.x = fmaxf(fmaf(x.x, scS[cb + 0], shS[cb + 0]), 0.f);
        x.y = fmaxf(fmaf(x.y, scS[cb + 1], shS[cb + 1]), 0.f);
        x.z = fmaxf(fmaf(x.z, scS[cb + 2], shS[cb + 2]), 0.f);
        x.w = fmaxf(fmaf(x.w, scS[cb + 3], shS[cb + 3]), 0.f);
        acc += x.x * w.x + x.y * w.y + x.z * w.z + x.w * w.w;
      }
      acc = waveReduceSum(acc);
      if (lane == 0) outm[idx] = acc + mb3[jj];
    }
  } else {
    // ================= projector chain (64 blocks) ==========================
    float (*As)[68] = (float(*)[68])smemF;             // 1088
    float (*Xs)[36] = (float(*)[36])(smemF + 1088);    // 576
    float* scS = smemF + 1664;                         // 512
    float* shS = smemF + 2176;                         // 512
    float* piS = smemF + 2688;                         // 36
    int pid = bid - 144;
    int b = pid >> 3, mt = pid & 7;
    proj_layer<false, true, true>(As, Xs, scS, shS, piS,
        pw1, pb1, vlad, t1, piraw, nullptr, nullptr, nullptr, nullptr, 0.f,
        ps1, pq1, HH, DD, b, mt * 64);
    shadowBar(flags + FOFF_P1, 64, pid);
    proj_layer<true, true, false>(As, Xs, scS, shS, piS,
        pw2, pb2, t1, t2, nullptr, ps1, pq1, pg1, pt1, (float)(BB * KC),
        ps2, pq2, HH, HH, b, mt * 64);
    shadowBar(flags + FOFF_P2, 64, pid);
    if (mt < 2)
      proj_layer<true, false, false>(As, Xs, scS, shS, piS,
          pw3, pb3, t2, outp, nullptr, ps2, pq2, pg2, pt2, (float)(BB * KC),
          nullptr, nullptr, PP, HH, b, mt * 64);
  }
}

// ---------------- launch ----------------
extern "C" void kernel_launch(void* const* d_in, const int* in_sizes, int n_in,
                              void* d_out, int out_size, void* d_ws, size_t ws_size,
                              hipStream_t stream) {
  const float* feat = (const float*)d_in[0];
  const float* cw1 = (const float*)d_in[1];  const float* cb1 = (const float*)d_in[2];
  const float* cg1 = (const float*)d_in[3];  const float* ct1 = (const float*)d_in[4];
  const float* cw2 = (const float*)d_in[5];  const float* cb2 = (const float*)d_in[6];
  const float* cg2 = (const float*)d_in[7];  const float* ct2 = (const float*)d_in[8];
  const float* cw3 = (const float*)d_in[9];  const float* cb3 = (const float*)d_in[10];
  const float* pw1 = (const float*)d_in[11]; const float* pb1 = (const float*)d_in[12];
  const float* pg1 = (const float*)d_in[13]; const float* pt1 = (const float*)d_in[14];
  const float* pw2 = (const float*)d_in[15]; const float* pb2 = (const float*)d_in[16];
  const float* pg2 = (const float*)d_in[17]; const float* pt2 = (const float*)d_in[18];
  const float* pw3 = (const float*)d_in[19]; const float* pb3 = (const float*)d_in[20];
  const float* mw1 = (const float*)d_in[21]; const float* mb1 = (const float*)d_in[22];
  const float* mg1 = (const float*)d_in[23]; const float* mt1 = (const float*)d_in[24];
  const float* mw2 = (const float*)d_in[25]; const float* mb2 = (const float*)d_in[26];
  const float* mg2 = (const float*)d_in[27]; const float* mt2 = (const float*)d_in[28];
  const float* mw3 = (const float*)d_in[29]; const float* mb3 = (const float*)d_in[30];
  float* out = (float*)d_out;

  // ---- workspace layout: post-GEMM2 buffers alias Y1 ----
  char* p = (char*)d_ws;
  size_t off = 0;
  auto alloc = [&](size_t bytes) { char* r = p + off; off = (off + bytes + 255) & ~(size_t)255; return r; };
  float* Y1 = (float*)alloc(67108864);   // [8][512][4096] f32
  float* Y2 = (float*)alloc(67108864);
  u16* W1H = (u16*)alloc(1048576); u16* W1M = (u16*)alloc(1048576); u16* W1L = (u16*)alloc(1048576);
  u16* W2H = (u16*)alloc(524288);  u16* W2M = (u16*)alloc(524288);  u16* W2L = (u16*)alloc(524288);
  u16* W3H = (u16*)alloc(32768);   u16* W3M = (u16*)alloc(32768);   u16* W3L = (u16*)alloc(32768);
  // BN accumulators: GS/GQ are 32-slot spread arrays; 69632 floats zeroed by convW3_all
  float* BNACC = (float*)alloc(278528);
  float* GS1 = BNACC + 0;      float* GQ1 = BNACC + 16384;
  float* GS2 = BNACC + 32768;  float* GQ2 = BNACC + 49152;
  float* MSS1 = BNACC + 65536; float* MSQ1 = BNACC + 66048;
  float* MSS2 = BNACC + 66560; float* MSQ2 = BNACC + 67072;
  float* PS1 = BNACC + 67584;  float* PQ1 = BNACC + 68096;
  float* PS2 = BNACC + 68608;  float* PQ2 = BNACC + 69120;
  // ---- sub-arena inside Y1's region: first written AFTER GEMM2 completes ----
  char* q = (char*)Y1;
  size_t qoff = 0;
  auto qalloc = [&](size_t bytes) { char* r = q + qoff; qoff = (qoff + bytes + 255) & ~(size_t)255; return r; };
  float* LSC  = (float*)qalloc(4194304);  // [8][32][4096], written by GEMM3
  float* SCRB = (float*)qalloc(4194304);  // score
  float* LSE  = (float*)qalloc(131072);
  u64*   GBUF = (u64*)qalloc(819200);     // 25*8*16*32 u64 pairs
  float* GMAX = (float*)qalloc(32768);
  float* MH1  = (float*)qalloc(16384);
  float* MH2  = (float*)qalloc(16384);
  float* T1   = (float*)qalloc(524288);
  float* T2   = (float*)qalloc(524288);
  // contiguous memset region: PIRAW | VLAD | COSTD | NFSQ | NMUSQ | FLAGS(16KB)
  const size_t MS_BYTES = 1024 + 1048576 + 4194304 + 131072 + 1024 + 16384;
  char* MS = qalloc(MS_BYTES);
  float* PIRAW = (float*)MS;
  float* VLAD  = (float*)(MS + 1024);
  float* COSTD = (float*)(MS + 1024 + 1048576);
  float* NFSQ  = (float*)(MS + 1024 + 1048576 + 4194304);
  float* NMUSQ = (float*)(MS + 1024 + 1048576 + 4194304 + 131072);
  unsigned* FLG = (unsigned*)(MS + 1024 + 1048576 + 4194304 + 131072 + 1024);

  hipMemsetAsync(d_out, 0, sizeof(float), stream);

  float logp = logf(1.0f / NP + 1e-8f);
  float logq = logf(1.0f / KC + 1e-8f);
  const float CNT_BN = (float)(BB * NP);     // 32768 (conv-score head BN)
  dim3 blk(256);

  // weight permute + 3-split + BNACC zeroing (one launch)
  convW3_all<<<dim3(4, 32, 3), blk, 0, stream>>>(
      cw1, W1H, W1M, W1L, cw2, W2H, W2M, W2L, cw3, W3H, W3M, W3L, BNACC);

  // GEMM1: bnstats fused (shfl-reduce + 32-slot spread atomics)
  gemm_mfma3<128, 4, 4, 4, 2, false, true, false><<<dim3(128, 1, 8), blk, 0, stream>>>(
      W1H, W1M, W1L, cb1, feat, nullptr, nullptr, nullptr, nullptr, 0.f,
      Y1, 1024, 512, GS1, GQ1, nullptr, nullptr, nullptr);
  // GEMM2: consumer-side BN (sums 32 slots); produces GS2/GQ2
  gemm_mfma3<128, 4, 4, 4, 2, true, true, false><<<dim3(128, 1, 8), blk, 0, stream>>>(
      W2H, W2M, W2L, cb2, Y1, GS1, GQ1, cg1, ct1, CNT_BN,
      Y2, 512, 512, GS2, GQ2, nullptr, nullptr, nullptr);
  // Y1 dead -> zero aliased accumulation buffers (PIRAW must precede GEMM3)
  hipMemsetAsync(MS, 0, MS_BYTES, stream);
  // GEMM3: consumer BN from GS2/GQ2 + fused softmax_pi epilogue
  gemm_mfma3<32, 1, 2, 2, 1, true, false, true><<<dim3(32, 1, 8), blk, 0, stream>>>(
      W3H, W3M, W3L, cb3, Y2, GS2, GQ2, cg2, ct2, CNT_BN,
      LSC, 512, 32, nullptr, nullptr, SCRB, LSE, PIRAW);

  // vlad (raw, undivided)
  vlad_accum<<<dim3(8, DD / 128, BB), blk, 0, stream>>>(feat, SCRB, VLAD);

  // cost dots + fused pi-divide / ||f||^2 / ||mu||^2 / gmax
  cost_accum<<<dim3(4, NP / 128, BB), blk, 0, stream>>>(
      feat, VLAD, PIRAW, COSTD, NFSQ, NMUSQ, GMAX);

  // tail: sinkhorn + MLP chain + projector chain in ONE launch (shadow execution)
  tail_all<<<dim3(208), blk, 0, stream>>>(
      COSTD, NFSQ, NMUSQ, GBUF, LSC, LSE, out, FLG, logp, logq,
      mw1, mb1, mg1, mt1, mw2, mb2, mg2, mt2, mw3, mb3,
      GMAX, MH1, MH2, out + 1 + BB * PP * KC, MSS1, MSQ1, MSS2, MSQ2,
      pw1, pb1, pg1, pt1, pw2, pb2, pg2, pt2, pw3, pb3,
      VLAD, PIRAW, T1, T2, out + 1, PS1, PQ1, PS2, PQ2);
}